// Round 1
// baseline (2366.384 us; speedup 1.0000x reference)
//
#include <hip/hip_runtime.h>
#include <math.h>

#define NN   30000
#define EE   480000
#define ETOT 510000   // EE + NN self loops
#define BB   48
#define HHH  4
#define DDD  64
#define CCH  256      // HHH*DDD
#define NINP 8
#define NOUTP 128
#define NLAY 10
#define SLOPE 0.2f
#define AGG_CAP 512

__device__ __forceinline__ float gelu_f(float x){
    return 0.5f * x * (1.0f + erff(x * 0.70710678118654752f));
}

// ---------------- CSR build ----------------
__global__ void count_k(const int* __restrict__ ei, int* __restrict__ cnt){
    int e = blockIdx.x * 256 + threadIdx.x;
    if (e >= ETOT) return;
    int d = (e < EE) ? ei[EE + e] : (e - EE);
    atomicAdd(&cnt[d], 1);
}

__global__ __launch_bounds__(1024) void scan_k(const int* __restrict__ cnt, int* __restrict__ row_ptr){
    __shared__ int sdata[1024];
    __shared__ int carry;
    int tid = threadIdx.x;
    if (tid == 0) carry = 0;
    __syncthreads();
    for (int base = 0; base < NN; base += 1024){
        int i = base + tid;
        int v = (i < NN) ? cnt[i] : 0;
        sdata[tid] = v;
        __syncthreads();
        for (int off = 1; off < 1024; off <<= 1){
            int t = (tid >= off) ? sdata[tid - off] : 0;
            __syncthreads();
            sdata[tid] += t;
            __syncthreads();
        }
        if (i < NN) row_ptr[i] = carry + sdata[tid] - v;   // exclusive
        __syncthreads();
        if (tid == 1023) carry += sdata[1023];
        __syncthreads();
    }
    if (tid == 0) row_ptr[NN] = carry;
}

__global__ void scatter_k(const int* __restrict__ ei, const int* __restrict__ row_ptr,
                          int* __restrict__ cursor, int* __restrict__ csr_src){
    int e = blockIdx.x * 256 + threadIdx.x;
    if (e >= ETOT) return;
    int s, d;
    if (e < EE){ s = ei[e]; d = ei[EE + e]; } else { s = d = e - EE; }
    int pos = row_ptr[d] + atomicAdd(&cursor[d], 1);
    csr_src[pos] = s;
}

// ---------------- layer 0 GEMM: [N,8] @ [8,256] ----------------
__global__ __launch_bounds__(256) void gemm_l0(const float* __restrict__ x,
                                               const float* __restrict__ W0,
                                               float* __restrict__ out){
    __shared__ float xs[NINP];
    int n = blockIdx.x;
    int c = threadIdx.x;
    if (c < NINP) xs[c] = x[n * NINP + c];
    __syncthreads();
    float acc = 0.f;
#pragma unroll
    for (int k = 0; k < NINP; ++k) acc += xs[k] * W0[k * CCH + c];
    out[n * CCH + c] = acc;
}

// ---------------- main GEMM: [N,256] @ [256,256] with optional gelu on input ----------------
#define BM 128
#define BN 128
#define BKK 16
__global__ __launch_bounds__(256) void gemm256(const float* __restrict__ A,
                                               const float* __restrict__ W,
                                               float* __restrict__ Cmat,
                                               int applyGelu){
    __shared__ float As[BKK][BM];    // transposed A tile
    __shared__ float Wsh[BKK][BN];
    int tid = threadIdx.x;
    int tx = tid & 15, ty = tid >> 4;
    int rowBase = blockIdx.y * BM;
    int colBase = blockIdx.x * BN;
    float acc[8][8];
#pragma unroll
    for (int i = 0; i < 8; ++i)
#pragma unroll
        for (int j = 0; j < 8; ++j) acc[i][j] = 0.f;

    for (int kb = 0; kb < CCH; kb += BKK){
#pragma unroll
        for (int i = 0; i < 2; ++i){
            int elem = (tid + i * 256) * 4;
            int r  = elem >> 4;        // /16
            int kc = elem & 15;
            int grow = rowBase + r;
            float4 v;
            if (grow < NN) v = *(const float4*)(A + (size_t)grow * CCH + kb + kc);
            else           v = make_float4(0.f, 0.f, 0.f, 0.f);
            if (applyGelu){
                v.x = gelu_f(v.x); v.y = gelu_f(v.y); v.z = gelu_f(v.z); v.w = gelu_f(v.w);
            }
            As[kc + 0][r] = v.x; As[kc + 1][r] = v.y; As[kc + 2][r] = v.z; As[kc + 3][r] = v.w;

            int k  = (tid + i * 256) >> 5;      // 0..15
            int c4 = (tid & 31) * 4;
            float4 wv = *(const float4*)(W + (size_t)(kb + k) * CCH + colBase + c4);
            *(float4*)&Wsh[k][c4] = wv;
        }
        __syncthreads();
#pragma unroll
        for (int kk = 0; kk < BKK; ++kk){
            float a[8], w[8];
            *(float4*)&a[0] = *(const float4*)&As[kk][ty * 8];
            *(float4*)&a[4] = *(const float4*)&As[kk][ty * 8 + 4];
            *(float4*)&w[0] = *(const float4*)&Wsh[kk][tx * 8];
            *(float4*)&w[4] = *(const float4*)&Wsh[kk][tx * 8 + 4];
#pragma unroll
            for (int i = 0; i < 8; ++i)
#pragma unroll
                for (int j = 0; j < 8; ++j) acc[i][j] += a[i] * w[j];
        }
        __syncthreads();
    }
#pragma unroll
    for (int i = 0; i < 8; ++i){
        int grow = rowBase + ty * 8 + i;
        if (grow < NN){
            float4 v0 = make_float4(acc[i][0], acc[i][1], acc[i][2], acc[i][3]);
            float4 v1 = make_float4(acc[i][4], acc[i][5], acc[i][6], acc[i][7]);
            *(float4*)(Cmat + (size_t)grow * CCH + colBase + tx * 8)     = v0;
            *(float4*)(Cmat + (size_t)grow * CCH + colBase + tx * 8 + 4) = v1;
        }
    }
}

// ---------------- alpha projections: [N,H] dots ----------------
__global__ void alpha_k(const float* __restrict__ h,
                        const float* __restrict__ a_src, const float* __restrict__ a_dst,
                        float* __restrict__ as_out, float* __restrict__ ad_out){
    int t = blockIdx.x * 256 + threadIdx.x;
    if (t >= NN * HHH) return;
    int n = t >> 2, hh = t & 3;
    const float4* hp = (const float4*)(h + (size_t)n * CCH + hh * DDD);
    const float4* sp = (const float4*)(a_src + hh * DDD);
    const float4* dp = (const float4*)(a_dst + hh * DDD);
    float s1 = 0.f, s2 = 0.f;
#pragma unroll
    for (int q = 0; q < DDD / 4; ++q){
        float4 hv = hp[q], sv = sp[q], dv = dp[q];
        s1 += hv.x * sv.x + hv.y * sv.y + hv.z * sv.z + hv.w * sv.w;
        s2 += hv.x * dv.x + hv.y * dv.y + hv.z * dv.z + hv.w * dv.w;
    }
    as_out[t] = s1;
    ad_out[t] = s2;
}

// ---------------- per-node softmax + aggregation ----------------
__global__ __launch_bounds__(256) void agg_k(const float* __restrict__ h,
                                             const float* __restrict__ asrc,
                                             const float* __restrict__ adst,
                                             const float* __restrict__ bias,
                                             const int* __restrict__ row_ptr,
                                             const int* __restrict__ csr_src,
                                             float* __restrict__ out){
    __shared__ float m_s[HHH], z_s[HHH];
    __shared__ float al_s[AGG_CAP * HHH];
    int n = blockIdx.x;
    int tid = threadIdx.x;
    int row0 = row_ptr[n];
    int deg = row_ptr[n + 1] - row0;
    int w = tid >> 6, lane = tid & 63;

    float adst_w = adst[n * HHH + w];
    float mmax = -INFINITY;
    for (int k = lane; k < deg; k += 64){
        int s = csr_src[row0 + k];
        float e = asrc[s * HHH + w] + adst_w;
        e = (e > 0.f) ? e : SLOPE * e;
        mmax = fmaxf(mmax, e);
    }
#pragma unroll
    for (int off = 32; off; off >>= 1) mmax = fmaxf(mmax, __shfl_xor(mmax, off));
    float zsum = 0.f;
    for (int k = lane; k < deg; k += 64){
        int s = csr_src[row0 + k];
        float e = asrc[s * HHH + w] + adst_w;
        e = (e > 0.f) ? e : SLOPE * e;
        float ex = __expf(e - mmax);
        if (k < AGG_CAP) al_s[k * HHH + w] = ex;
        zsum += ex;
    }
#pragma unroll
    for (int off = 32; off; off >>= 1) zsum += __shfl_xor(zsum, off);
    if (lane == 0){ m_s[w] = mmax; z_s[w] = zsum; }
    __syncthreads();

    int c = tid, hh = c >> 6;
    float m = m_s[hh];
    float invz = 1.f / (z_s[hh] + 1e-16f);
    float adst_h = adst[n * HHH + hh];
    float acc = 0.f;
    for (int k = 0; k < deg; ++k){
        int s = csr_src[row0 + k];
        float al;
        if (k < AGG_CAP){
            al = al_s[k * HHH + hh] * invz;
        } else {
            float e = asrc[s * HHH + hh] + adst_h;
            e = (e > 0.f) ? e : SLOPE * e;
            al = __expf(e - m) * invz;
        }
        acc += h[(size_t)s * CCH + c] * al;
    }
    out[(size_t)n * CCH + c] = acc + bias[c];
}

// ---------------- graph boundary pointers (batch is sorted) ----------------
__global__ void gptr_k(const int* __restrict__ batch, int* __restrict__ gptr){
    int i = blockIdx.x * 256 + threadIdx.x;
    if (i >= NN) return;
    int bi = batch[i];
    int bp = (i == 0) ? -1 : batch[i - 1];
    for (int g = bp + 1; g <= bi; ++g) gptr[g] = i;
    if (i == NN - 1){
        for (int g = bi + 1; g <= BB; ++g) gptr[g] = NN;
    }
}

// ---------------- pooling: min/max/mean/sum per graph ----------------
__global__ __launch_bounds__(256) void pool_k(const float* __restrict__ h,
                                              const int* __restrict__ gptr,
                                              float* __restrict__ gbuf){
    int b = blockIdx.x;
    int c = threadIdx.x;
    int s = gptr[b], e = gptr[b + 1];
    float mn = INFINITY, mx = -INFINITY, sm = 0.f;
    for (int n = s; n < e; ++n){
        float v = h[(size_t)n * CCH + c];
        mn = fminf(mn, v); mx = fmaxf(mx, v); sm += v;
    }
    int cnt = e - s;
    float mean = sm / fmaxf((float)cnt, 1.0f);
    if (cnt == 0){ mn = 0.f; mx = 0.f; }
    gbuf[b * 4 * CCH + 0 * CCH + c] = mn;
    gbuf[b * 4 * CCH + 1 * CCH + c] = mx;
    gbuf[b * 4 * CCH + 2 * CCH + c] = mean;
    gbuf[b * 4 * CCH + 3 * CCH + c] = sm;
}

// ---------------- head: gelu(g) @ head_W + head_b ----------------
__global__ __launch_bounds__(128) void head_k(const float* __restrict__ gbuf,
                                              const float* __restrict__ head_W,
                                              const float* __restrict__ head_b,
                                              float* __restrict__ out){
    __shared__ float gs[4 * CCH];
    int b = blockIdx.x;
    int o = threadIdx.x;
    for (int k = o; k < 4 * CCH; k += 128) gs[k] = gelu_f(gbuf[b * 4 * CCH + k]);
    __syncthreads();
    float acc = head_b[o];
    for (int k = 0; k < 4 * CCH; ++k) acc += gs[k] * head_W[k * NOUTP + o];
    out[b * NOUTP + o] = acc;
}

extern "C" void kernel_launch(void* const* d_in, const int* in_sizes, int n_in,
                              void* d_out, int out_size, void* d_ws, size_t ws_size,
                              hipStream_t stream){
    const float* x        = (const float*)d_in[0];
    const int*   ei       = (const int*)  d_in[1];
    const int*   batch    = (const int*)  d_in[2];
    const float* W0       = (const float*)d_in[3];
    const float* a_src0   = (const float*)d_in[4];
    const float* a_dst0   = (const float*)d_in[5];
    const float* b0       = (const float*)d_in[6];
    const float* Ws       = (const float*)d_in[7];
    const float* a_srcs   = (const float*)d_in[8];
    const float* a_dsts   = (const float*)d_in[9];
    const float* bs       = (const float*)d_in[10];
    const float* head_W   = (const float*)d_in[11];
    const float* head_b   = (const float*)d_in[12];
    float* out = (float*)d_out;

    char* p = (char*)d_ws;
    float* buf0 = (float*)p;            p += (size_t)NN * CCH * 4;
    float* buf1 = (float*)p;            p += (size_t)NN * CCH * 4;
    float* asb  = (float*)p;            p += (size_t)NN * HHH * 4;
    float* adb  = (float*)p;            p += (size_t)NN * HHH * 4;
    int* row_ptr = (int*)p;             p += 120016;               // (N+1)*4 padded
    int* cnt     = (int*)p;             p += (size_t)NN * 4;
    int* csr_src = (int*)p;             p += (size_t)ETOT * 4;
    float* gbuf  = (float*)p;           p += (size_t)BB * 4 * CCH * 4;
    int* gptr    = (int*)p;             p += 208;

    // ---- CSR build ----
    hipMemsetAsync(cnt, 0, (size_t)NN * 4, stream);
    count_k<<<(ETOT + 255) / 256, 256, 0, stream>>>(ei, cnt);
    scan_k<<<1, 1024, 0, stream>>>(cnt, row_ptr);
    hipMemsetAsync(cnt, 0, (size_t)NN * 4, stream);
    scatter_k<<<(ETOT + 255) / 256, 256, 0, stream>>>(ei, row_ptr, cnt, csr_src);
    gptr_k<<<(NN + 255) / 256, 256, 0, stream>>>(batch, gptr);

    // ---- layer 0 ----
    gemm_l0<<<NN, 256, 0, stream>>>(x, W0, buf1);
    alpha_k<<<(NN * HHH + 255) / 256, 256, 0, stream>>>(buf1, a_src0, a_dst0, asb, adb);
    agg_k<<<NN, 256, 0, stream>>>(buf1, asb, adb, b0, row_ptr, csr_src, buf0);

    // ---- layers 1..9 ----
    dim3 ggrid(CCH / BN, (NN + BM - 1) / BM);
    for (int l = 1; l < NLAY; ++l){
        const float* Wl  = Ws     + (size_t)(l - 1) * CCH * CCH;
        const float* asl = a_srcs + (size_t)(l - 1) * HHH * DDD;
        const float* adl = a_dsts + (size_t)(l - 1) * HHH * DDD;
        const float* bl  = bs     + (size_t)(l - 1) * CCH;
        gemm256<<<ggrid, 256, 0, stream>>>(buf0, Wl, buf1, 1);
        alpha_k<<<(NN * HHH + 255) / 256, 256, 0, stream>>>(buf1, asl, adl, asb, adb);
        agg_k<<<NN, 256, 0, stream>>>(buf1, asb, adb, bl, row_ptr, csr_src, buf0);
    }

    // ---- readout ----
    pool_k<<<BB, 256, 0, stream>>>(buf0, gptr, gbuf);
    head_k<<<BB, 128, 0, stream>>>(gbuf, head_W, head_b, out);
}

// Round 2
// 2099.773 us; speedup vs baseline: 1.1270x; 1.1270x over previous
//
#include <hip/hip_runtime.h>
#include <math.h>

#define NN   30000
#define EE   480000
#define ETOT 510000   // EE + NN self loops
#define BB   48
#define HHH  4
#define DDD  64
#define CCH  256      // HHH*DDD
#define NINP 8
#define NOUTP 128
#define NLAY 10
#define SLOPE 0.2f
#define MAXD 192      // LDS capacity for per-node edge list (deg ~ Poisson(17), max ~45)
#define PCHUNK 32     // pool stage-1 chunks per graph

__device__ __forceinline__ float gelu_f(float x){
    return 0.5f * x * (1.0f + erff(x * 0.70710678118654752f));
}

// ---------------- CSR build ----------------
__global__ void count_k(const int* __restrict__ ei, int* __restrict__ cnt){
    int e = blockIdx.x * 256 + threadIdx.x;
    if (e >= ETOT) return;
    int d = (e < EE) ? ei[EE + e] : (e - EE);
    atomicAdd(&cnt[d], 1);
}

__global__ __launch_bounds__(1024) void scan_k(const int* __restrict__ cnt, int* __restrict__ row_ptr){
    __shared__ int sdata[1024];
    __shared__ int carry;
    int tid = threadIdx.x;
    if (tid == 0) carry = 0;
    __syncthreads();
    for (int base = 0; base < NN; base += 1024){
        int i = base + tid;
        int v = (i < NN) ? cnt[i] : 0;
        sdata[tid] = v;
        __syncthreads();
        for (int off = 1; off < 1024; off <<= 1){
            int t = (tid >= off) ? sdata[tid - off] : 0;
            __syncthreads();
            sdata[tid] += t;
            __syncthreads();
        }
        if (i < NN) row_ptr[i] = carry + sdata[tid] - v;   // exclusive
        __syncthreads();
        if (tid == 1023) carry += sdata[1023];
        __syncthreads();
    }
    if (tid == 0) row_ptr[NN] = carry;
}

__global__ void scatter_k(const int* __restrict__ ei, const int* __restrict__ row_ptr,
                          int* __restrict__ cursor, int* __restrict__ csr_src){
    int e = blockIdx.x * 256 + threadIdx.x;
    if (e >= ETOT) return;
    int s, d;
    if (e < EE){ s = ei[e]; d = ei[EE + e]; } else { s = d = e - EE; }
    int pos = row_ptr[d] + atomicAdd(&cursor[d], 1);
    csr_src[pos] = s;
}

// ---------------- layer 0 GEMM: [N,8] @ [8,256] ----------------
__global__ __launch_bounds__(256) void gemm_l0(const float* __restrict__ x,
                                               const float* __restrict__ W0,
                                               float* __restrict__ out){
    __shared__ float xs[NINP];
    int n = blockIdx.x;
    int c = threadIdx.x;
    if (c < NINP) xs[c] = x[n * NINP + c];
    __syncthreads();
    float acc = 0.f;
#pragma unroll
    for (int k = 0; k < NINP; ++k) acc += xs[k] * W0[k * CCH + c];
    out[n * CCH + c] = acc;
}

// ---------------- main GEMM: [N,256] @ [256,256] with optional gelu on input ----------------
#define BM 128
#define BN 128
#define BKK 16
__global__ __launch_bounds__(256) void gemm256(const float* __restrict__ A,
                                               const float* __restrict__ W,
                                               float* __restrict__ Cmat,
                                               int applyGelu){
    __shared__ float As[BKK][BM];    // transposed A tile
    __shared__ float Wsh[BKK][BN];
    int tid = threadIdx.x;
    int tx = tid & 15, ty = tid >> 4;
    int rowBase = blockIdx.y * BM;
    int colBase = blockIdx.x * BN;
    float acc[8][8];
#pragma unroll
    for (int i = 0; i < 8; ++i)
#pragma unroll
        for (int j = 0; j < 8; ++j) acc[i][j] = 0.f;

    for (int kb = 0; kb < CCH; kb += BKK){
#pragma unroll
        for (int i = 0; i < 2; ++i){
            int elem = (tid + i * 256) * 4;
            int r  = elem >> 4;        // /16
            int kc = elem & 15;
            int grow = rowBase + r;
            float4 v;
            if (grow < NN) v = *(const float4*)(A + (size_t)grow * CCH + kb + kc);
            else           v = make_float4(0.f, 0.f, 0.f, 0.f);
            if (applyGelu){
                v.x = gelu_f(v.x); v.y = gelu_f(v.y); v.z = gelu_f(v.z); v.w = gelu_f(v.w);
            }
            As[kc + 0][r] = v.x; As[kc + 1][r] = v.y; As[kc + 2][r] = v.z; As[kc + 3][r] = v.w;

            int k  = (tid + i * 256) >> 5;      // 0..15
            int c4 = (tid & 31) * 4;
            float4 wv = *(const float4*)(W + (size_t)(kb + k) * CCH + colBase + c4);
            *(float4*)&Wsh[k][c4] = wv;
        }
        __syncthreads();
#pragma unroll
        for (int kk = 0; kk < BKK; ++kk){
            float a[8], w[8];
            *(float4*)&a[0] = *(const float4*)&As[kk][ty * 8];
            *(float4*)&a[4] = *(const float4*)&As[kk][ty * 8 + 4];
            *(float4*)&w[0] = *(const float4*)&Wsh[kk][tx * 8];
            *(float4*)&w[4] = *(const float4*)&Wsh[kk][tx * 8 + 4];
#pragma unroll
            for (int i = 0; i < 8; ++i)
#pragma unroll
                for (int j = 0; j < 8; ++j) acc[i][j] += a[i] * w[j];
        }
        __syncthreads();
    }
#pragma unroll
    for (int i = 0; i < 8; ++i){
        int grow = rowBase + ty * 8 + i;
        if (grow < NN){
            float4 v0 = make_float4(acc[i][0], acc[i][1], acc[i][2], acc[i][3]);
            float4 v1 = make_float4(acc[i][4], acc[i][5], acc[i][6], acc[i][7]);
            *(float4*)(Cmat + (size_t)grow * CCH + colBase + tx * 8)     = v0;
            *(float4*)(Cmat + (size_t)grow * CCH + colBase + tx * 8 + 4) = v1;
        }
    }
}

// ---------------- alpha projections: [N,H] dots ----------------
__global__ void alpha_k(const float* __restrict__ h,
                        const float* __restrict__ a_src, const float* __restrict__ a_dst,
                        float* __restrict__ as_out, float* __restrict__ ad_out){
    int t = blockIdx.x * 256 + threadIdx.x;
    if (t >= NN * HHH) return;
    int n = t >> 2, hh = t & 3;
    const float4* hp = (const float4*)(h + (size_t)n * CCH + hh * DDD);
    const float4* sp = (const float4*)(a_src + hh * DDD);
    const float4* dp = (const float4*)(a_dst + hh * DDD);
    float s1 = 0.f, s2 = 0.f;
#pragma unroll
    for (int q = 0; q < DDD / 4; ++q){
        float4 hv = hp[q], sv = sp[q], dv = dp[q];
        s1 += hv.x * sv.x + hv.y * sv.y + hv.z * sv.z + hv.w * sv.w;
        s2 += hv.x * dv.x + hv.y * dv.y + hv.z * dv.z + hv.w * dv.w;
    }
    as_out[t] = s1;
    ad_out[t] = s2;
}

// ---------------- per-node softmax + aggregation (latency-optimized) ----------------
// Block = 1 node, 256 threads. Phase 1: wave w computes softmax alphas for head w
// into LDS. Phase 2: wave w processes edges k ≡ w (mod 4); each lane reads float4
// (16B) of h[src]; 4 waves x unroll-2 = 8 outstanding 1KB row gathers per block.
__global__ __launch_bounds__(256) void agg_k(const float* __restrict__ h,
                                             const float* __restrict__ asrc,
                                             const float* __restrict__ adst,
                                             const float* __restrict__ bias,
                                             const int* __restrict__ row_ptr,
                                             const int* __restrict__ csr_src,
                                             float* __restrict__ out){
    __shared__ int   s_idx[MAXD];
    __shared__ float s_al[MAXD * HHH];
    __shared__ float m_s[HHH], iz_s[HHH];
    __shared__ float red[HHH][CCH];

    int n = blockIdx.x;
    int tid = threadIdx.x;
    int row0 = row_ptr[n];
    int deg  = row_ptr[n + 1] - row0;
    int hh   = tid >> 6;       // wave id
    int lane = tid & 63;
    int kcap = (deg < MAXD) ? deg : MAXD;

    for (int k = tid; k < kcap; k += 256) s_idx[k] = csr_src[row0 + k];
    __syncthreads();

    // ---- phase 1: softmax alphas for head hh (one wave per head) ----
    float adst_h = adst[n * HHH + hh];
    float m = -INFINITY;
    for (int k = lane; k < deg; k += 64){
        int s = (k < MAXD) ? s_idx[k] : csr_src[row0 + k];
        float e = asrc[s * HHH + hh] + adst_h;
        e = (e > 0.f) ? e : SLOPE * e;
        if (k < MAXD) s_al[k * HHH + hh] = e;
        m = fmaxf(m, e);
    }
#pragma unroll
    for (int off = 32; off; off >>= 1) m = fmaxf(m, __shfl_xor(m, off));
    float z = 0.f;
    for (int k = lane; k < deg; k += 64){
        float e;
        if (k < MAXD) e = s_al[k * HHH + hh];
        else {
            int s = csr_src[row0 + k];
            e = asrc[s * HHH + hh] + adst_h;
            e = (e > 0.f) ? e : SLOPE * e;
        }
        float ex = __expf(e - m);
        if (k < MAXD) s_al[k * HHH + hh] = ex;
        z += ex;
    }
#pragma unroll
    for (int off = 32; off; off >>= 1) z += __shfl_xor(z, off);
    float invz = 1.f / (z + 1e-16f);
    for (int k = lane; k < kcap; k += 64) s_al[k * HHH + hh] *= invz;
    if (lane == 0){ m_s[hh] = m; iz_s[hh] = invz; }
    __syncthreads();

    // ---- phase 2: gather h rows, k split across waves ----
    int coff = lane << 2;           // this lane's 4 channels [coff, coff+4)
    int hc   = lane >> 4;           // head those channels belong to
    float4 acc = make_float4(0.f, 0.f, 0.f, 0.f);
    int k = hh;
    for (; k + 4 < kcap; k += 8){
        int s0 = s_idx[k], s1 = s_idx[k + 4];
        float a0 = s_al[k * HHH + hc];
        float a1 = s_al[(k + 4) * HHH + hc];
        float4 v0 = *(const float4*)(h + (size_t)s0 * CCH + coff);
        float4 v1 = *(const float4*)(h + (size_t)s1 * CCH + coff);
        acc.x += v0.x * a0 + v1.x * a1;
        acc.y += v0.y * a0 + v1.y * a1;
        acc.z += v0.z * a0 + v1.z * a1;
        acc.w += v0.w * a0 + v1.w * a1;
    }
    for (; k < kcap; k += 4){
        int s0 = s_idx[k];
        float a0 = s_al[k * HHH + hc];
        float4 v0 = *(const float4*)(h + (size_t)s0 * CCH + coff);
        acc.x += v0.x * a0; acc.y += v0.y * a0; acc.z += v0.z * a0; acc.w += v0.w * a0;
    }
    if (deg > MAXD){
        float adst_c = adst[n * HHH + hc];
        float mm = m_s[hc], iz = iz_s[hc];
        for (; k < deg; k += 4){
            int s0 = csr_src[row0 + k];
            float e = asrc[s0 * HHH + hc] + adst_c;
            e = (e > 0.f) ? e : SLOPE * e;
            float a0 = __expf(e - mm) * iz;
            float4 v0 = *(const float4*)(h + (size_t)s0 * CCH + coff);
            acc.x += v0.x * a0; acc.y += v0.y * a0; acc.z += v0.z * a0; acc.w += v0.w * a0;
        }
    }
    *(float4*)&red[hh][coff] = acc;
    __syncthreads();

    float r = red[0][tid] + red[1][tid] + red[2][tid] + red[3][tid];
    out[(size_t)n * CCH + tid] = r + bias[tid];
}

// ---------------- graph boundary pointers (batch is sorted) ----------------
__global__ void gptr_k(const int* __restrict__ batch, int* __restrict__ gptr){
    int i = blockIdx.x * 256 + threadIdx.x;
    if (i >= NN) return;
    int bi = batch[i];
    int bp = (i == 0) ? -1 : batch[i - 1];
    for (int g = bp + 1; g <= bi; ++g) gptr[g] = i;
    if (i == NN - 1){
        for (int g = bi + 1; g <= BB; ++g) gptr[g] = NN;
    }
}

// ---------------- pooling stage 1: per (graph, chunk) partials ----------------
__global__ __launch_bounds__(256) void pool1_k(const float* __restrict__ h,
                                               const int* __restrict__ gptr,
                                               float* __restrict__ part){
    const int S1 = BB * PCHUNK * CCH;
    int b = blockIdx.x, j = blockIdx.y, c = threadIdx.x;
    int s = gptr[b], e = gptr[b + 1];
    int len = e - s;
    int per = (len + PCHUNK - 1) / PCHUNK;
    int r0 = s + j * per;
    int r1 = r0 + per; if (r1 > e) r1 = e;
    float mn = INFINITY, mx = -INFINITY, sm = 0.f;
    int n = r0;
    for (; n + 4 <= r1; n += 4){
        float v0 = h[(size_t)(n + 0) * CCH + c];
        float v1 = h[(size_t)(n + 1) * CCH + c];
        float v2 = h[(size_t)(n + 2) * CCH + c];
        float v3 = h[(size_t)(n + 3) * CCH + c];
        mn = fminf(mn, fminf(fminf(v0, v1), fminf(v2, v3)));
        mx = fmaxf(mx, fmaxf(fmaxf(v0, v1), fmaxf(v2, v3)));
        sm += (v0 + v1) + (v2 + v3);
    }
    for (; n < r1; ++n){
        float v = h[(size_t)n * CCH + c];
        mn = fminf(mn, v); mx = fmaxf(mx, v); sm += v;
    }
    size_t o = ((size_t)b * PCHUNK + j) * CCH + c;
    part[o] = mn; part[S1 + o] = mx; part[2 * (size_t)S1 + o] = sm;
}

// ---------------- pooling stage 2: combine chunks ----------------
__global__ __launch_bounds__(256) void pool2_k(const float* __restrict__ part,
                                               const int* __restrict__ gptr,
                                               float* __restrict__ gbuf){
    const int S1 = BB * PCHUNK * CCH;
    int b = blockIdx.x, c = threadIdx.x;
    float mn = INFINITY, mx = -INFINITY, sm = 0.f;
#pragma unroll
    for (int j = 0; j < PCHUNK; ++j){
        size_t o = ((size_t)b * PCHUNK + j) * CCH + c;
        mn = fminf(mn, part[o]);
        mx = fmaxf(mx, part[S1 + o]);
        sm += part[2 * (size_t)S1 + o];
    }
    int cnt = gptr[b + 1] - gptr[b];
    float mean = sm / fmaxf((float)cnt, 1.0f);
    if (cnt == 0){ mn = 0.f; mx = 0.f; }
    gbuf[b * 4 * CCH + 0 * CCH + c] = mn;
    gbuf[b * 4 * CCH + 1 * CCH + c] = mx;
    gbuf[b * 4 * CCH + 2 * CCH + c] = mean;
    gbuf[b * 4 * CCH + 3 * CCH + c] = sm;
}

// ---------------- head: gelu(g) @ head_W + head_b ----------------
__global__ __launch_bounds__(128) void head_k(const float* __restrict__ gbuf,
                                              const float* __restrict__ head_W,
                                              const float* __restrict__ head_b,
                                              float* __restrict__ out){
    __shared__ float gs[4 * CCH];
    int b = blockIdx.x;
    int o = threadIdx.x;
    for (int k = o; k < 4 * CCH; k += 128) gs[k] = gelu_f(gbuf[b * 4 * CCH + k]);
    __syncthreads();
    float acc = head_b[o];
    for (int k = 0; k < 4 * CCH; ++k) acc += gs[k] * head_W[k * NOUTP + o];
    out[b * NOUTP + o] = acc;
}

extern "C" void kernel_launch(void* const* d_in, const int* in_sizes, int n_in,
                              void* d_out, int out_size, void* d_ws, size_t ws_size,
                              hipStream_t stream){
    const float* x        = (const float*)d_in[0];
    const int*   ei       = (const int*)  d_in[1];
    const int*   batch    = (const int*)  d_in[2];
    const float* W0       = (const float*)d_in[3];
    const float* a_src0   = (const float*)d_in[4];
    const float* a_dst0   = (const float*)d_in[5];
    const float* b0       = (const float*)d_in[6];
    const float* Ws       = (const float*)d_in[7];
    const float* a_srcs   = (const float*)d_in[8];
    const float* a_dsts   = (const float*)d_in[9];
    const float* bs       = (const float*)d_in[10];
    const float* head_W   = (const float*)d_in[11];
    const float* head_b   = (const float*)d_in[12];
    float* out = (float*)d_out;

    char* p = (char*)d_ws;
    float* buf0 = (float*)p;            p += (size_t)NN * CCH * 4;
    float* buf1 = (float*)p;            p += (size_t)NN * CCH * 4;
    float* asb  = (float*)p;            p += (size_t)NN * HHH * 4;
    float* adb  = (float*)p;            p += (size_t)NN * HHH * 4;
    int* row_ptr = (int*)p;             p += 120016;               // (N+1)*4 padded
    int* cnt     = (int*)p;             p += (size_t)NN * 4;
    int* csr_src = (int*)p;             p += (size_t)ETOT * 4;
    float* gbuf  = (float*)p;           p += (size_t)BB * 4 * CCH * 4;
    int* gptr    = (int*)p;             p += 208;

    // ---- CSR build ----
    hipMemsetAsync(cnt, 0, (size_t)NN * 4, stream);
    count_k<<<(ETOT + 255) / 256, 256, 0, stream>>>(ei, cnt);
    scan_k<<<1, 1024, 0, stream>>>(cnt, row_ptr);
    hipMemsetAsync(cnt, 0, (size_t)NN * 4, stream);
    scatter_k<<<(ETOT + 255) / 256, 256, 0, stream>>>(ei, row_ptr, cnt, csr_src);
    gptr_k<<<(NN + 255) / 256, 256, 0, stream>>>(batch, gptr);

    // ---- layer 0 ----
    gemm_l0<<<NN, 256, 0, stream>>>(x, W0, buf1);
    alpha_k<<<(NN * HHH + 255) / 256, 256, 0, stream>>>(buf1, a_src0, a_dst0, asb, adb);
    agg_k<<<NN, 256, 0, stream>>>(buf1, asb, adb, b0, row_ptr, csr_src, buf0);

    // ---- layers 1..9 ----
    dim3 ggrid(CCH / BN, (NN + BM - 1) / BM);
    for (int l = 1; l < NLAY; ++l){
        const float* Wl  = Ws     + (size_t)(l - 1) * CCH * CCH;
        const float* asl = a_srcs + (size_t)(l - 1) * HHH * DDD;
        const float* adl = a_dsts + (size_t)(l - 1) * HHH * DDD;
        const float* bl  = bs     + (size_t)(l - 1) * CCH;
        gemm256<<<ggrid, 256, 0, stream>>>(buf0, Wl, buf1, 1);
        alpha_k<<<(NN * HHH + 255) / 256, 256, 0, stream>>>(buf1, asl, adl, asb, adb);
        agg_k<<<NN, 256, 0, stream>>>(buf1, asb, adb, bl, row_ptr, csr_src, buf0);
    }

    // ---- readout: two-stage pooling (buf1 is free scratch here) ----
    dim3 pgrid(BB, PCHUNK);
    pool1_k<<<pgrid, 256, 0, stream>>>(buf0, gptr, buf1);
    pool2_k<<<BB, 256, 0, stream>>>(buf1, gptr, gbuf);
    head_k<<<BB, 128, 0, stream>>>(gbuf, head_W, head_b, out);
}

// Round 3
// 1604.052 us; speedup vs baseline: 1.4753x; 1.3090x over previous
//
#include <hip/hip_runtime.h>
#include <math.h>

#define NN   30000
#define EE   480000
#define ETOT 510000   // EE + NN self loops
#define BB   48
#define HHH  4
#define DDD  64
#define CCH  256      // HHH*DDD
#define NINP 8
#define NOUTP 128
#define NLAY 10
#define SLOPE 0.2f
#define MAXD 192      // LDS capacity for per-node edge list
#define PCHUNK 32     // pool stage-1 chunks per graph

typedef short v8s  __attribute__((ext_vector_type(8)));
typedef float v4f  __attribute__((ext_vector_type(4)));

__device__ __forceinline__ float gelu_f(float x){
    return 0.5f * x * (1.0f + erff(x * 0.70710678118654752f));
}
__device__ __forceinline__ unsigned short f2bf(float f){
    unsigned u = __float_as_uint(f);
    unsigned r = u + 0x7FFF + ((u >> 16) & 1);   // RNE
    return (unsigned short)(r >> 16);
}
__device__ __forceinline__ float bf2f(unsigned short b){
    return __uint_as_float(((unsigned)b) << 16);
}

// ---------------- CSR build ----------------
__global__ void count_k(const int* __restrict__ ei, int* __restrict__ cnt){
    int e = blockIdx.x * 256 + threadIdx.x;
    if (e >= ETOT) return;
    int d = (e < EE) ? ei[EE + e] : (e - EE);
    atomicAdd(&cnt[d], 1);
}

__global__ __launch_bounds__(1024) void scan_k(const int* __restrict__ cnt, int* __restrict__ row_ptr){
    __shared__ int sdata[1024];
    __shared__ int carry;
    int tid = threadIdx.x;
    if (tid == 0) carry = 0;
    __syncthreads();
    for (int base = 0; base < NN; base += 1024){
        int i = base + tid;
        int v = (i < NN) ? cnt[i] : 0;
        sdata[tid] = v;
        __syncthreads();
        for (int off = 1; off < 1024; off <<= 1){
            int t = (tid >= off) ? sdata[tid - off] : 0;
            __syncthreads();
            sdata[tid] += t;
            __syncthreads();
        }
        if (i < NN) row_ptr[i] = carry + sdata[tid] - v;   // exclusive
        __syncthreads();
        if (tid == 1023) carry += sdata[1023];
        __syncthreads();
    }
    if (tid == 0) row_ptr[NN] = carry;
}

__global__ void scatter_k(const int* __restrict__ ei, const int* __restrict__ row_ptr,
                          int* __restrict__ cursor, int* __restrict__ csr_src){
    int e = blockIdx.x * 256 + threadIdx.x;
    if (e >= ETOT) return;
    int s, d;
    if (e < EE){ s = ei[e]; d = ei[EE + e]; } else { s = d = e - EE; }
    int pos = row_ptr[d] + atomicAdd(&cursor[d], 1);
    csr_src[pos] = s;
}

// ---------------- weight prep: transpose + split to bf16 hi/lo ----------------
__global__ __launch_bounds__(256) void wconv_k(const float* __restrict__ Ws,
                                               unsigned short* __restrict__ WT_hi,
                                               unsigned short* __restrict__ WT_lo){
    int l = blockIdx.x;
    int n = threadIdx.x;
    const float* W = Ws + (size_t)l * CCH * CCH;
    unsigned short* th = WT_hi + (size_t)l * CCH * CCH;
    unsigned short* tl = WT_lo + (size_t)l * CCH * CCH;
    for (int k = 0; k < CCH; ++k){
        float w = W[k * CCH + n];
        unsigned short h = f2bf(w);
        th[n * CCH + k] = h;
        tl[n * CCH + k] = f2bf(w - bf2f(h));
    }
}

// ---------------- layer 0 GEMM: [N,8] @ [8,256] ----------------
__global__ __launch_bounds__(256) void gemm_l0(const float* __restrict__ x,
                                               const float* __restrict__ W0,
                                               float* __restrict__ out){
    __shared__ float xs[NINP];
    int n = blockIdx.x;
    int c = threadIdx.x;
    if (c < NINP) xs[c] = x[n * NINP + c];
    __syncthreads();
    float acc = 0.f;
#pragma unroll
    for (int k = 0; k < NINP; ++k) acc += xs[k] * W0[k * CCH + c];
    out[n * CCH + c] = acc;
}

// ---------------- main GEMM: gelu(A) @ W via split-bf16 MFMA ----------------
// Block 256 thr = 4 waves (2x2), tile 128x128, wave tile 64x64 = 4x4 MFMA 16x16x32.
// A loaded fp32 in fragment layout (A[m=lane&15][k=(lane>>4)*8+j]), gelu'd and
// split hi/lo in-register. W pre-transposed+split (WT[n][k]) so B fragments are
// contiguous 16B. 3 MFMA products: hi*hi + lo*hi + hi*lo (error ~2^-16).
__global__ __launch_bounds__(256) void gemm_mfma(const float* __restrict__ A,
                                                 const unsigned short* __restrict__ Bhi,
                                                 const unsigned short* __restrict__ Blo,
                                                 float* __restrict__ C){
    int tid  = threadIdx.x;
    int lane = tid & 63, wave = tid >> 6;
    int wr = wave >> 1, wc = wave & 1;
    int rowBase = blockIdx.y * 128 + wr * 64;
    int colBase = blockIdx.x * 128 + wc * 64;
    int fr = lane & 15;      // fragment row (A) / col (B,D)
    int kg = lane >> 4;      // k-group 0..3

    v4f acc[4][4];
#pragma unroll
    for (int mi = 0; mi < 4; ++mi)
#pragma unroll
        for (int ni = 0; ni < 4; ++ni) acc[mi][ni] = (v4f){0.f, 0.f, 0.f, 0.f};

    const float* aptr[4];
#pragma unroll
    for (int mi = 0; mi < 4; ++mi){
        int r = rowBase + mi * 16 + fr;
        if (r >= NN) r = NN - 1;                  // clamp; C store guarded below
        aptr[mi] = A + (size_t)r * CCH + kg * 8;
    }
    const unsigned short* bhp[4];
    const unsigned short* blp[4];
#pragma unroll
    for (int ni = 0; ni < 4; ++ni){
        int c = colBase + ni * 16 + fr;
        bhp[ni] = Bhi + (size_t)c * CCH + kg * 8;
        blp[ni] = Blo + (size_t)c * CCH + kg * 8;
    }

    for (int kc = 0; kc < CCH; kc += 32){
        v8s ah[4], al[4], bh[4], bl[4];
#pragma unroll
        for (int mi = 0; mi < 4; ++mi){
            float4 v0 = *(const float4*)(aptr[mi] + kc);
            float4 v1 = *(const float4*)(aptr[mi] + kc + 4);
            float f[8] = {v0.x, v0.y, v0.z, v0.w, v1.x, v1.y, v1.z, v1.w};
            v8s hi, lo;
#pragma unroll
            for (int j = 0; j < 8; ++j){
                float g = gelu_f(f[j]);
                unsigned short hb = f2bf(g);
                hi[j] = (short)hb;
                lo[j] = (short)f2bf(g - bf2f(hb));
            }
            ah[mi] = hi; al[mi] = lo;
        }
#pragma unroll
        for (int ni = 0; ni < 4; ++ni){
            bh[ni] = *(const v8s*)(bhp[ni] + kc);
            bl[ni] = *(const v8s*)(blp[ni] + kc);
        }
#pragma unroll
        for (int mi = 0; mi < 4; ++mi)
#pragma unroll
            for (int ni = 0; ni < 4; ++ni){
                acc[mi][ni] = __builtin_amdgcn_mfma_f32_16x16x32_bf16(ah[mi], bh[ni], acc[mi][ni], 0, 0, 0);
                acc[mi][ni] = __builtin_amdgcn_mfma_f32_16x16x32_bf16(al[mi], bh[ni], acc[mi][ni], 0, 0, 0);
                acc[mi][ni] = __builtin_amdgcn_mfma_f32_16x16x32_bf16(ah[mi], bl[ni], acc[mi][ni], 0, 0, 0);
            }
    }

    // D layout: col = lane&15 (=fr), row = (lane>>4)*4 + j (=kg*4+j)
#pragma unroll
    for (int mi = 0; mi < 4; ++mi)
#pragma unroll
        for (int j = 0; j < 4; ++j){
            int r = rowBase + mi * 16 + kg * 4 + j;
            if (r < NN){
#pragma unroll
                for (int ni = 0; ni < 4; ++ni)
                    C[(size_t)r * CCH + colBase + ni * 16 + fr] = acc[mi][ni][j];
            }
        }
}

// ---------------- alpha projections: [N,H] dots ----------------
__global__ void alpha_k(const float* __restrict__ h,
                        const float* __restrict__ a_src, const float* __restrict__ a_dst,
                        float* __restrict__ as_out, float* __restrict__ ad_out){
    int t = blockIdx.x * 256 + threadIdx.x;
    if (t >= NN * HHH) return;
    int n = t >> 2, hh = t & 3;
    const float4* hp = (const float4*)(h + (size_t)n * CCH + hh * DDD);
    const float4* sp = (const float4*)(a_src + hh * DDD);
    const float4* dp = (const float4*)(a_dst + hh * DDD);
    float s1 = 0.f, s2 = 0.f;
#pragma unroll
    for (int q = 0; q < DDD / 4; ++q){
        float4 hv = hp[q], sv = sp[q], dv = dp[q];
        s1 += hv.x * sv.x + hv.y * sv.y + hv.z * sv.z + hv.w * sv.w;
        s2 += hv.x * dv.x + hv.y * dv.y + hv.z * dv.z + hv.w * dv.w;
    }
    as_out[t] = s1;
    ad_out[t] = s2;
}

// ---------------- per-node softmax + aggregation ----------------
__global__ __launch_bounds__(256) void agg_k(const float* __restrict__ h,
                                             const float* __restrict__ asrc,
                                             const float* __restrict__ adst,
                                             const float* __restrict__ bias,
                                             const int* __restrict__ row_ptr,
                                             const int* __restrict__ csr_src,
                                             float* __restrict__ out){
    __shared__ int   s_idx[MAXD];
    __shared__ float s_al[MAXD * HHH];
    __shared__ float m_s[HHH], iz_s[HHH];
    __shared__ float red[HHH][CCH];

    int n = blockIdx.x;
    int tid = threadIdx.x;
    int row0 = row_ptr[n];
    int deg  = row_ptr[n + 1] - row0;
    int hh   = tid >> 6;       // wave id
    int lane = tid & 63;
    int kcap = (deg < MAXD) ? deg : MAXD;

    for (int k = tid; k < kcap; k += 256) s_idx[k] = csr_src[row0 + k];
    __syncthreads();

    float adst_h = adst[n * HHH + hh];
    float m = -INFINITY;
    for (int k = lane; k < deg; k += 64){
        int s = (k < MAXD) ? s_idx[k] : csr_src[row0 + k];
        float e = asrc[s * HHH + hh] + adst_h;
        e = (e > 0.f) ? e : SLOPE * e;
        if (k < MAXD) s_al[k * HHH + hh] = e;
        m = fmaxf(m, e);
    }
#pragma unroll
    for (int off = 32; off; off >>= 1) m = fmaxf(m, __shfl_xor(m, off));
    float z = 0.f;
    for (int k = lane; k < deg; k += 64){
        float e;
        if (k < MAXD) e = s_al[k * HHH + hh];
        else {
            int s = csr_src[row0 + k];
            e = asrc[s * HHH + hh] + adst_h;
            e = (e > 0.f) ? e : SLOPE * e;
        }
        float ex = __expf(e - m);
        if (k < MAXD) s_al[k * HHH + hh] = ex;
        z += ex;
    }
#pragma unroll
    for (int off = 32; off; off >>= 1) z += __shfl_xor(z, off);
    float invz = 1.f / (z + 1e-16f);
    for (int k = lane; k < kcap; k += 64) s_al[k * HHH + hh] *= invz;
    if (lane == 0){ m_s[hh] = m; iz_s[hh] = invz; }
    __syncthreads();

    int coff = lane << 2;
    int hc   = lane >> 4;
    float4 acc = make_float4(0.f, 0.f, 0.f, 0.f);
    int k = hh;
    for (; k + 4 < kcap; k += 8){
        int s0 = s_idx[k], s1 = s_idx[k + 4];
        float a0 = s_al[k * HHH + hc];
        float a1 = s_al[(k + 4) * HHH + hc];
        float4 v0 = *(const float4*)(h + (size_t)s0 * CCH + coff);
        float4 v1 = *(const float4*)(h + (size_t)s1 * CCH + coff);
        acc.x += v0.x * a0 + v1.x * a1;
        acc.y += v0.y * a0 + v1.y * a1;
        acc.z += v0.z * a0 + v1.z * a1;
        acc.w += v0.w * a0 + v1.w * a1;
    }
    for (; k < kcap; k += 4){
        int s0 = s_idx[k];
        float a0 = s_al[k * HHH + hc];
        float4 v0 = *(const float4*)(h + (size_t)s0 * CCH + coff);
        acc.x += v0.x * a0; acc.y += v0.y * a0; acc.z += v0.z * a0; acc.w += v0.w * a0;
    }
    if (deg > MAXD){
        float adst_c = adst[n * HHH + hc];
        float mm = m_s[hc], iz = iz_s[hc];
        for (; k < deg; k += 4){
            int s0 = csr_src[row0 + k];
            float e = asrc[s0 * HHH + hc] + adst_c;
            e = (e > 0.f) ? e : SLOPE * e;
            float a0 = __expf(e - mm) * iz;
            float4 v0 = *(const float4*)(h + (size_t)s0 * CCH + coff);
            acc.x += v0.x * a0; acc.y += v0.y * a0; acc.z += v0.z * a0; acc.w += v0.w * a0;
        }
    }
    *(float4*)&red[hh][coff] = acc;
    __syncthreads();

    float r = red[0][tid] + red[1][tid] + red[2][tid] + red[3][tid];
    out[(size_t)n * CCH + tid] = r + bias[tid];
}

// ---------------- graph boundary pointers (batch is sorted) ----------------
__global__ void gptr_k(const int* __restrict__ batch, int* __restrict__ gptr){
    int i = blockIdx.x * 256 + threadIdx.x;
    if (i >= NN) return;
    int bi = batch[i];
    int bp = (i == 0) ? -1 : batch[i - 1];
    for (int g = bp + 1; g <= bi; ++g) gptr[g] = i;
    if (i == NN - 1){
        for (int g = bi + 1; g <= BB; ++g) gptr[g] = NN;
    }
}

// ---------------- pooling stage 1 ----------------
__global__ __launch_bounds__(256) void pool1_k(const float* __restrict__ h,
                                               const int* __restrict__ gptr,
                                               float* __restrict__ part){
    const int S1 = BB * PCHUNK * CCH;
    int b = blockIdx.x, j = blockIdx.y, c = threadIdx.x;
    int s = gptr[b], e = gptr[b + 1];
    int len = e - s;
    int per = (len + PCHUNK - 1) / PCHUNK;
    int r0 = s + j * per;
    int r1 = r0 + per; if (r1 > e) r1 = e;
    float mn = INFINITY, mx = -INFINITY, sm = 0.f;
    int n = r0;
    for (; n + 4 <= r1; n += 4){
        float v0 = h[(size_t)(n + 0) * CCH + c];
        float v1 = h[(size_t)(n + 1) * CCH + c];
        float v2 = h[(size_t)(n + 2) * CCH + c];
        float v3 = h[(size_t)(n + 3) * CCH + c];
        mn = fminf(mn, fminf(fminf(v0, v1), fminf(v2, v3)));
        mx = fmaxf(mx, fmaxf(fmaxf(v0, v1), fmaxf(v2, v3)));
        sm += (v0 + v1) + (v2 + v3);
    }
    for (; n < r1; ++n){
        float v = h[(size_t)n * CCH + c];
        mn = fminf(mn, v); mx = fmaxf(mx, v); sm += v;
    }
    size_t o = ((size_t)b * PCHUNK + j) * CCH + c;
    part[o] = mn; part[S1 + o] = mx; part[2 * (size_t)S1 + o] = sm;
}

// ---------------- pooling stage 2 ----------------
__global__ __launch_bounds__(256) void pool2_k(const float* __restrict__ part,
                                               const int* __restrict__ gptr,
                                               float* __restrict__ gbuf){
    const int S1 = BB * PCHUNK * CCH;
    int b = blockIdx.x, c = threadIdx.x;
    float mn = INFINITY, mx = -INFINITY, sm = 0.f;
#pragma unroll
    for (int j = 0; j < PCHUNK; ++j){
        size_t o = ((size_t)b * PCHUNK + j) * CCH + c;
        mn = fminf(mn, part[o]);
        mx = fmaxf(mx, part[S1 + o]);
        sm += part[2 * (size_t)S1 + o];
    }
    int cnt = gptr[b + 1] - gptr[b];
    float mean = sm / fmaxf((float)cnt, 1.0f);
    if (cnt == 0){ mn = 0.f; mx = 0.f; }
    gbuf[b * 4 * CCH + 0 * CCH + c] = mn;
    gbuf[b * 4 * CCH + 1 * CCH + c] = mx;
    gbuf[b * 4 * CCH + 2 * CCH + c] = mean;
    gbuf[b * 4 * CCH + 3 * CCH + c] = sm;
}

// ---------------- head: gelu(g) @ head_W + head_b ----------------
__global__ __launch_bounds__(128) void head_k(const float* __restrict__ gbuf,
                                              const float* __restrict__ head_W,
                                              const float* __restrict__ head_b,
                                              float* __restrict__ out){
    __shared__ float gs[4 * CCH];
    int b = blockIdx.x;
    int o = threadIdx.x;
    for (int k = o; k < 4 * CCH; k += 128) gs[k] = gelu_f(gbuf[b * 4 * CCH + k]);
    __syncthreads();
    float acc = head_b[o];
    for (int k = 0; k < 4 * CCH; ++k) acc += gs[k] * head_W[k * NOUTP + o];
    out[b * NOUTP + o] = acc;
}

extern "C" void kernel_launch(void* const* d_in, const int* in_sizes, int n_in,
                              void* d_out, int out_size, void* d_ws, size_t ws_size,
                              hipStream_t stream){
    const float* x        = (const float*)d_in[0];
    const int*   ei       = (const int*)  d_in[1];
    const int*   batch    = (const int*)  d_in[2];
    const float* W0       = (const float*)d_in[3];
    const float* a_src0   = (const float*)d_in[4];
    const float* a_dst0   = (const float*)d_in[5];
    const float* b0       = (const float*)d_in[6];
    const float* Ws       = (const float*)d_in[7];
    const float* a_srcs   = (const float*)d_in[8];
    const float* a_dsts   = (const float*)d_in[9];
    const float* bs       = (const float*)d_in[10];
    const float* head_W   = (const float*)d_in[11];
    const float* head_b   = (const float*)d_in[12];
    float* out = (float*)d_out;

    char* p = (char*)d_ws;
    float* buf0 = (float*)p;            p += (size_t)NN * CCH * 4;
    float* buf1 = (float*)p;            p += (size_t)NN * CCH * 4;
    float* asb  = (float*)p;            p += (size_t)NN * HHH * 4;
    float* adb  = (float*)p;            p += (size_t)NN * HHH * 4;
    int* row_ptr = (int*)p;             p += 120016;               // (N+1)*4 padded
    int* cnt     = (int*)p;             p += (size_t)NN * 4;
    int* csr_src = (int*)p;             p += (size_t)ETOT * 4;
    float* gbuf  = (float*)p;           p += (size_t)BB * 4 * CCH * 4;
    int* gptr    = (int*)p;             p += 208;
    unsigned short* wthi = (unsigned short*)p; p += (size_t)(NLAY - 1) * CCH * CCH * 2;
    unsigned short* wtlo = (unsigned short*)p; p += (size_t)(NLAY - 1) * CCH * CCH * 2;

    // ---- CSR build + weight prep ----
    hipMemsetAsync(cnt, 0, (size_t)NN * 4, stream);
    count_k<<<(ETOT + 255) / 256, 256, 0, stream>>>(ei, cnt);
    scan_k<<<1, 1024, 0, stream>>>(cnt, row_ptr);
    hipMemsetAsync(cnt, 0, (size_t)NN * 4, stream);
    scatter_k<<<(ETOT + 255) / 256, 256, 0, stream>>>(ei, row_ptr, cnt, csr_src);
    gptr_k<<<(NN + 255) / 256, 256, 0, stream>>>(batch, gptr);
    wconv_k<<<NLAY - 1, 256, 0, stream>>>(Ws, wthi, wtlo);

    // ---- layer 0 ----
    gemm_l0<<<NN, 256, 0, stream>>>(x, W0, buf1);
    alpha_k<<<(NN * HHH + 255) / 256, 256, 0, stream>>>(buf1, a_src0, a_dst0, asb, adb);
    agg_k<<<NN, 256, 0, stream>>>(buf1, asb, adb, b0, row_ptr, csr_src, buf0);

    // ---- layers 1..9 ----
    dim3 ggrid(2, (NN + 127) / 128);
    for (int l = 1; l < NLAY; ++l){
        const unsigned short* whl = wthi + (size_t)(l - 1) * CCH * CCH;
        const unsigned short* wll = wtlo + (size_t)(l - 1) * CCH * CCH;
        const float* asl = a_srcs + (size_t)(l - 1) * HHH * DDD;
        const float* adl = a_dsts + (size_t)(l - 1) * HHH * DDD;
        const float* bl  = bs     + (size_t)(l - 1) * CCH;
        gemm_mfma<<<ggrid, 256, 0, stream>>>(buf0, whl, wll, buf1);
        alpha_k<<<(NN * HHH + 255) / 256, 256, 0, stream>>>(buf1, asl, adl, asb, adb);
        agg_k<<<NN, 256, 0, stream>>>(buf1, asb, adb, bl, row_ptr, csr_src, buf0);
    }

    // ---- readout ----
    dim3 pgrid(BB, PCHUNK);
    pool1_k<<<pgrid, 256, 0, stream>>>(buf0, gptr, buf1);
    pool2_k<<<BB, 256, 0, stream>>>(buf1, gptr, gbuf);
    head_k<<<BB, 128, 0, stream>>>(gbuf, head_W, head_b, out);
}

// Round 4
// 1490.311 us; speedup vs baseline: 1.5878x; 1.0763x over previous
//
#include <hip/hip_runtime.h>
#include <math.h>

#define NN   30000
#define EE   480000
#define ETOT 510000   // EE + NN self loops
#define BB   48
#define HHH  4
#define DDD  64
#define CCH  256      // HHH*DDD
#define NINP 8
#define NOUTP 128
#define NLAY 10
#define SLOPE 0.2f
#define PCHUNK 32     // pool stage-1 chunks per graph

typedef short v8s  __attribute__((ext_vector_type(8)));
typedef float v4f  __attribute__((ext_vector_type(4)));

__device__ __forceinline__ float gelu_f(float x){
    return 0.5f * x * (1.0f + erff(x * 0.70710678118654752f));
}
__device__ __forceinline__ unsigned short f2bf(float f){
    unsigned u = __float_as_uint(f);
    unsigned r = u + 0x7FFF + ((u >> 16) & 1);   // RNE
    return (unsigned short)(r >> 16);
}
__device__ __forceinline__ float bf2f(unsigned short b){
    return __uint_as_float(((unsigned)b) << 16);
}
__device__ __forceinline__ float lrelu(float e){
    return (e > 0.f) ? e : SLOPE * e;
}

// ---------------- CSR build ----------------
__global__ void count_k(const int* __restrict__ ei, int* __restrict__ cnt){
    int e = blockIdx.x * 256 + threadIdx.x;
    if (e >= ETOT) return;
    int d = (e < EE) ? ei[EE + e] : (e - EE);
    atomicAdd(&cnt[d], 1);
}

__global__ __launch_bounds__(1024) void scan_k(const int* __restrict__ cnt, int* __restrict__ row_ptr){
    __shared__ int sdata[1024];
    __shared__ int carry;
    int tid = threadIdx.x;
    if (tid == 0) carry = 0;
    __syncthreads();
    for (int base = 0; base < NN; base += 1024){
        int i = base + tid;
        int v = (i < NN) ? cnt[i] : 0;
        sdata[tid] = v;
        __syncthreads();
        for (int off = 1; off < 1024; off <<= 1){
            int t = (tid >= off) ? sdata[tid - off] : 0;
            __syncthreads();
            sdata[tid] += t;
            __syncthreads();
        }
        if (i < NN) row_ptr[i] = carry + sdata[tid] - v;   // exclusive
        __syncthreads();
        if (tid == 1023) carry += sdata[1023];
        __syncthreads();
    }
    if (tid == 0) row_ptr[NN] = carry;
}

__global__ void scatter_k(const int* __restrict__ ei, const int* __restrict__ row_ptr,
                          int* __restrict__ cursor, int* __restrict__ csr_src){
    int e = blockIdx.x * 256 + threadIdx.x;
    if (e >= ETOT) return;
    int s, d;
    if (e < EE){ s = ei[e]; d = ei[EE + e]; } else { s = d = e - EE; }
    int pos = row_ptr[d] + atomicAdd(&cursor[d], 1);
    csr_src[pos] = s;
}

// ---------------- weight prep: transpose + split to bf16 hi/lo ----------------
__global__ __launch_bounds__(256) void wconv_k(const float* __restrict__ Ws,
                                               unsigned short* __restrict__ WT_hi,
                                               unsigned short* __restrict__ WT_lo){
    int l = blockIdx.x;
    int n = threadIdx.x;
    int k0 = blockIdx.y * 32;
    const float* W = Ws + (size_t)l * CCH * CCH;
    unsigned short* th = WT_hi + (size_t)l * CCH * CCH;
    unsigned short* tl = WT_lo + (size_t)l * CCH * CCH;
    for (int k = k0; k < k0 + 32; ++k){
        float w = W[k * CCH + n];
        unsigned short h = f2bf(w);
        th[n * CCH + k] = h;
        tl[n * CCH + k] = f2bf(w - bf2f(h));
    }
}

// ---------------- layer 0 GEMM: [N,8] @ [8,256] ----------------
__global__ __launch_bounds__(256) void gemm_l0(const float* __restrict__ x,
                                               const float* __restrict__ W0,
                                               float* __restrict__ out){
    __shared__ float xs[NINP];
    int n = blockIdx.x;
    int c = threadIdx.x;
    if (c < NINP) xs[c] = x[n * NINP + c];
    __syncthreads();
    float acc = 0.f;
#pragma unroll
    for (int k = 0; k < NINP; ++k) acc += xs[k] * W0[k * CCH + c];
    out[n * CCH + c] = acc;
}

// ---------------- main GEMM: gelu(A) @ W via split-bf16 MFMA ----------------
__global__ __launch_bounds__(256) void gemm_mfma(const float* __restrict__ A,
                                                 const unsigned short* __restrict__ Bhi,
                                                 const unsigned short* __restrict__ Blo,
                                                 float* __restrict__ C){
    int tid  = threadIdx.x;
    int lane = tid & 63, wave = tid >> 6;
    int wr = wave >> 1, wc = wave & 1;
    int rowBase = blockIdx.y * 128 + wr * 64;
    int colBase = blockIdx.x * 128 + wc * 64;
    int fr = lane & 15;      // fragment row (A) / col (B,D)
    int kg = lane >> 4;      // k-group 0..3

    v4f acc[4][4];
#pragma unroll
    for (int mi = 0; mi < 4; ++mi)
#pragma unroll
        for (int ni = 0; ni < 4; ++ni) acc[mi][ni] = (v4f){0.f, 0.f, 0.f, 0.f};

    const float* aptr[4];
#pragma unroll
    for (int mi = 0; mi < 4; ++mi){
        int r = rowBase + mi * 16 + fr;
        if (r >= NN) r = NN - 1;                  // clamp; C store guarded below
        aptr[mi] = A + (size_t)r * CCH + kg * 8;
    }
    const unsigned short* bhp[4];
    const unsigned short* blp[4];
#pragma unroll
    for (int ni = 0; ni < 4; ++ni){
        int c = colBase + ni * 16 + fr;
        bhp[ni] = Bhi + (size_t)c * CCH + kg * 8;
        blp[ni] = Blo + (size_t)c * CCH + kg * 8;
    }

    for (int kc = 0; kc < CCH; kc += 32){
        v8s ah[4], al[4], bh[4], bl[4];
#pragma unroll
        for (int mi = 0; mi < 4; ++mi){
            float4 v0 = *(const float4*)(aptr[mi] + kc);
            float4 v1 = *(const float4*)(aptr[mi] + kc + 4);
            float f[8] = {v0.x, v0.y, v0.z, v0.w, v1.x, v1.y, v1.z, v1.w};
            v8s hi, lo;
#pragma unroll
            for (int j = 0; j < 8; ++j){
                float g = gelu_f(f[j]);
                unsigned short hb = f2bf(g);
                hi[j] = (short)hb;
                lo[j] = (short)f2bf(g - bf2f(hb));
            }
            ah[mi] = hi; al[mi] = lo;
        }
#pragma unroll
        for (int ni = 0; ni < 4; ++ni){
            bh[ni] = *(const v8s*)(bhp[ni] + kc);
            bl[ni] = *(const v8s*)(blp[ni] + kc);
        }
#pragma unroll
        for (int mi = 0; mi < 4; ++mi)
#pragma unroll
            for (int ni = 0; ni < 4; ++ni){
                acc[mi][ni] = __builtin_amdgcn_mfma_f32_16x16x32_bf16(ah[mi], bh[ni], acc[mi][ni], 0, 0, 0);
                acc[mi][ni] = __builtin_amdgcn_mfma_f32_16x16x32_bf16(al[mi], bh[ni], acc[mi][ni], 0, 0, 0);
                acc[mi][ni] = __builtin_amdgcn_mfma_f32_16x16x32_bf16(ah[mi], bl[ni], acc[mi][ni], 0, 0, 0);
            }
    }

    // D layout: col = lane&15 (=fr), row = (lane>>4)*4 + j (=kg*4+j)
#pragma unroll
    for (int mi = 0; mi < 4; ++mi)
#pragma unroll
        for (int j = 0; j < 4; ++j){
            int r = rowBase + mi * 16 + kg * 4 + j;
            if (r < NN){
#pragma unroll
                for (int ni = 0; ni < 4; ++ni)
                    C[(size_t)r * CCH + colBase + ni * 16 + fr] = acc[mi][ni][j];
            }
        }
}

// ---------------- alpha projections: [N,H] dots ----------------
__global__ void alpha_k(const float* __restrict__ h,
                        const float* __restrict__ a_src, const float* __restrict__ a_dst,
                        float* __restrict__ as_out, float* __restrict__ ad_out){
    int t = blockIdx.x * 256 + threadIdx.x;
    if (t >= NN * HHH) return;
    int n = t >> 2, hh = t & 3;
    const float4* hp = (const float4*)(h + (size_t)n * CCH + hh * DDD);
    const float4* sp = (const float4*)(a_src + hh * DDD);
    const float4* dp = (const float4*)(a_dst + hh * DDD);
    float s1 = 0.f, s2 = 0.f;
#pragma unroll
    for (int q = 0; q < DDD / 4; ++q){
        float4 hv = hp[q], sv = sp[q], dv = dp[q];
        s1 += hv.x * sv.x + hv.y * sv.y + hv.z * sv.z + hv.w * sv.w;
        s2 += hv.x * dv.x + hv.y * dv.y + hv.z * dv.z + hv.w * dv.w;
    }
    as_out[t] = s1;
    ad_out[t] = s2;
}

// ---------------- per-node softmax + aggregation: ONE WAVE PER NODE ----------------
// Block = 256 thr = 4 waves = 4 nodes. Lane k owns edge k (fast path deg<=64;
// generic online-softmax chunk path otherwise). Softmax is shuffle-only; alphas
// and indices parked in a per-wave LDS strip (no __syncthreads anywhere).
// Gather loop unrolled x4: each wave streams full 1KB h-rows (float4/lane).
__global__ __launch_bounds__(256) void agg_k(const float* __restrict__ h,
                                             const float* __restrict__ asrc,
                                             const float* __restrict__ adst,
                                             const float* __restrict__ bias,
                                             const int* __restrict__ row_ptr,
                                             const int* __restrict__ csr_src,
                                             float* __restrict__ out){
    __shared__ float s_al[4][64 * HHH];
    __shared__ int   s_ix[4][64];

    int wave = threadIdx.x >> 6, lane = threadIdx.x & 63;
    int n = blockIdx.x * 4 + wave;
    int row0 = row_ptr[n];
    int deg  = row_ptr[n + 1] - row0;
    float4 ad = *(const float4*)(adst + (size_t)n * HHH);
    int coff = lane << 2;        // this lane's 4 channels
    int hc   = lane >> 4;        // head those channels belong to
    float* al_w = s_al[wave];
    int*   ix_w = s_ix[wave];
    float4 acc = make_float4(0.f, 0.f, 0.f, 0.f);

    if (deg <= 64){
        // ---- fast path: lane k = edge k ----
        int k = lane;
        int s = 0;
        float e0 = -INFINITY, e1 = -INFINITY, e2 = -INFINITY, e3 = -INFINITY;
        if (k < deg){
            s = csr_src[row0 + k];
            float4 as = *(const float4*)(asrc + (size_t)s * HHH);
            e0 = lrelu(as.x + ad.x); e1 = lrelu(as.y + ad.y);
            e2 = lrelu(as.z + ad.z); e3 = lrelu(as.w + ad.w);
        }
        float m0 = e0, m1 = e1, m2 = e2, m3 = e3;
#pragma unroll
        for (int off = 32; off; off >>= 1){
            m0 = fmaxf(m0, __shfl_xor(m0, off));
            m1 = fmaxf(m1, __shfl_xor(m1, off));
            m2 = fmaxf(m2, __shfl_xor(m2, off));
            m3 = fmaxf(m3, __shfl_xor(m3, off));
        }
        float x0 = 0.f, x1 = 0.f, x2 = 0.f, x3 = 0.f;
        if (k < deg){
            x0 = __expf(e0 - m0); x1 = __expf(e1 - m1);
            x2 = __expf(e2 - m2); x3 = __expf(e3 - m3);
        }
        float z0 = x0, z1 = x1, z2 = x2, z3 = x3;
#pragma unroll
        for (int off = 32; off; off >>= 1){
            z0 += __shfl_xor(z0, off);
            z1 += __shfl_xor(z1, off);
            z2 += __shfl_xor(z2, off);
            z3 += __shfl_xor(z3, off);
        }
        if (k < deg){
            float4 alv;
            alv.x = x0 / (z0 + 1e-16f);
            alv.y = x1 / (z1 + 1e-16f);
            alv.z = x2 / (z2 + 1e-16f);
            alv.w = x3 / (z3 + 1e-16f);
            ix_w[k] = s;
            *(float4*)&al_w[k * HHH] = alv;
        }
        // ---- gather (lgkmcnt orders LDS write->read within the wave) ----
        int kk = 0;
        for (; kk + 4 <= deg; kk += 4){
            int i0 = ix_w[kk], i1 = ix_w[kk + 1], i2 = ix_w[kk + 2], i3 = ix_w[kk + 3];
            float a0 = al_w[kk * HHH + hc];
            float a1 = al_w[(kk + 1) * HHH + hc];
            float a2 = al_w[(kk + 2) * HHH + hc];
            float a3 = al_w[(kk + 3) * HHH + hc];
            float4 v0 = *(const float4*)(h + (size_t)i0 * CCH + coff);
            float4 v1 = *(const float4*)(h + (size_t)i1 * CCH + coff);
            float4 v2 = *(const float4*)(h + (size_t)i2 * CCH + coff);
            float4 v3 = *(const float4*)(h + (size_t)i3 * CCH + coff);
            acc.x += v0.x * a0 + v1.x * a1 + v2.x * a2 + v3.x * a3;
            acc.y += v0.y * a0 + v1.y * a1 + v2.y * a2 + v3.y * a3;
            acc.z += v0.z * a0 + v1.z * a1 + v2.z * a2 + v3.z * a3;
            acc.w += v0.w * a0 + v1.w * a1 + v2.w * a2 + v3.w * a3;
        }
        for (; kk < deg; ++kk){
            int i0 = ix_w[kk];
            float a0 = al_w[kk * HHH + hc];
            float4 v0 = *(const float4*)(h + (size_t)i0 * CCH + coff);
            acc.x += v0.x * a0; acc.y += v0.y * a0; acc.z += v0.z * a0; acc.w += v0.w * a0;
        }
    } else {
        // ---- generic path: online softmax over 64-edge chunks ----
        float m0 = -INFINITY, m1 = -INFINITY, m2 = -INFINITY, m3 = -INFINITY;
        float z0 = 0.f, z1 = 0.f, z2 = 0.f, z3 = 0.f;
        for (int c0 = 0; c0 < deg; c0 += 64){
            int k = c0 + lane;
            float e0 = -INFINITY, e1 = -INFINITY, e2 = -INFINITY, e3 = -INFINITY;
            if (k < deg){
                int s = csr_src[row0 + k];
                float4 as = *(const float4*)(asrc + (size_t)s * HHH);
                e0 = lrelu(as.x + ad.x); e1 = lrelu(as.y + ad.y);
                e2 = lrelu(as.z + ad.z); e3 = lrelu(as.w + ad.w);
            }
            float c0m = e0, c1m = e1, c2m = e2, c3m = e3;
#pragma unroll
            for (int off = 32; off; off >>= 1){
                c0m = fmaxf(c0m, __shfl_xor(c0m, off));
                c1m = fmaxf(c1m, __shfl_xor(c1m, off));
                c2m = fmaxf(c2m, __shfl_xor(c2m, off));
                c3m = fmaxf(c3m, __shfl_xor(c3m, off));
            }
            float n0 = fmaxf(m0, c0m), n1 = fmaxf(m1, c1m);
            float n2 = fmaxf(m2, c2m), n3 = fmaxf(m3, c3m);
            float x0 = 0.f, x1 = 0.f, x2 = 0.f, x3 = 0.f;
            if (k < deg){
                x0 = __expf(e0 - n0); x1 = __expf(e1 - n1);
                x2 = __expf(e2 - n2); x3 = __expf(e3 - n3);
            }
            float s0 = x0, s1 = x1, s2 = x2, s3 = x3;
#pragma unroll
            for (int off = 32; off; off >>= 1){
                s0 += __shfl_xor(s0, off);
                s1 += __shfl_xor(s1, off);
                s2 += __shfl_xor(s2, off);
                s3 += __shfl_xor(s3, off);
            }
            z0 = z0 * ((m0 == -INFINITY) ? 0.f : __expf(m0 - n0)) + s0;
            z1 = z1 * ((m1 == -INFINITY) ? 0.f : __expf(m1 - n1)) + s1;
            z2 = z2 * ((m2 == -INFINITY) ? 0.f : __expf(m2 - n2)) + s2;
            z3 = z3 * ((m3 == -INFINITY) ? 0.f : __expf(m3 - n3)) + s3;
            m0 = n0; m1 = n1; m2 = n2; m3 = n3;
        }
        float iz0 = 1.f / (z0 + 1e-16f), iz1 = 1.f / (z1 + 1e-16f);
        float iz2 = 1.f / (z2 + 1e-16f), iz3 = 1.f / (z3 + 1e-16f);
        for (int c0 = 0; c0 < deg; c0 += 64){
            int k = c0 + lane;
            if (k < deg){
                int s = csr_src[row0 + k];
                float4 as = *(const float4*)(asrc + (size_t)s * HHH);
                float4 alv;
                alv.x = __expf(lrelu(as.x + ad.x) - m0) * iz0;
                alv.y = __expf(lrelu(as.y + ad.y) - m1) * iz1;
                alv.z = __expf(lrelu(as.z + ad.z) - m2) * iz2;
                alv.w = __expf(lrelu(as.w + ad.w) - m3) * iz3;
                ix_w[lane] = s;
                *(float4*)&al_w[lane * HHH] = alv;
            }
            int cnt = deg - c0; if (cnt > 64) cnt = 64;
            for (int j = 0; j < cnt; ++j){
                int i0 = ix_w[j];
                float a0 = al_w[j * HHH + hc];
                float4 v0 = *(const float4*)(h + (size_t)i0 * CCH + coff);
                acc.x += v0.x * a0; acc.y += v0.y * a0; acc.z += v0.z * a0; acc.w += v0.w * a0;
            }
        }
    }

    float4 bv = *(const float4*)(bias + coff);
    acc.x += bv.x; acc.y += bv.y; acc.z += bv.z; acc.w += bv.w;
    *(float4*)(out + (size_t)n * CCH + coff) = acc;
}

// ---------------- graph boundary pointers (batch is sorted) ----------------
__global__ void gptr_k(const int* __restrict__ batch, int* __restrict__ gptr){
    int i = blockIdx.x * 256 + threadIdx.x;
    if (i >= NN) return;
    int bi = batch[i];
    int bp = (i == 0) ? -1 : batch[i - 1];
    for (int g = bp + 1; g <= bi; ++g) gptr[g] = i;
    if (i == NN - 1){
        for (int g = bi + 1; g <= BB; ++g) gptr[g] = NN;
    }
}

// ---------------- pooling stage 1 ----------------
__global__ __launch_bounds__(256) void pool1_k(const float* __restrict__ h,
                                               const int* __restrict__ gptr,
                                               float* __restrict__ part){
    const int S1 = BB * PCHUNK * CCH;
    int b = blockIdx.x, j = blockIdx.y, c = threadIdx.x;
    int s = gptr[b], e = gptr[b + 1];
    int len = e - s;
    int per = (len + PCHUNK - 1) / PCHUNK;
    int r0 = s + j * per;
    int r1 = r0 + per; if (r1 > e) r1 = e;
    float mn = INFINITY, mx = -INFINITY, sm = 0.f;
    int n = r0;
    for (; n + 4 <= r1; n += 4){
        float v0 = h[(size_t)(n + 0) * CCH + c];
        float v1 = h[(size_t)(n + 1) * CCH + c];
        float v2 = h[(size_t)(n + 2) * CCH + c];
        float v3 = h[(size_t)(n + 3) * CCH + c];
        mn = fminf(mn, fminf(fminf(v0, v1), fminf(v2, v3)));
        mx = fmaxf(mx, fmaxf(fmaxf(v0, v1), fmaxf(v2, v3)));
        sm += (v0 + v1) + (v2 + v3);
    }
    for (; n < r1; ++n){
        float v = h[(size_t)n * CCH + c];
        mn = fminf(mn, v); mx = fmaxf(mx, v); sm += v;
    }
    size_t o = ((size_t)b * PCHUNK + j) * CCH + c;
    part[o] = mn; part[S1 + o] = mx; part[2 * (size_t)S1 + o] = sm;
}

// ---------------- pooling stage 2 ----------------
__global__ __launch_bounds__(256) void pool2_k(const float* __restrict__ part,
                                               const int* __restrict__ gptr,
                                               float* __restrict__ gbuf){
    const int S1 = BB * PCHUNK * CCH;
    int b = blockIdx.x, c = threadIdx.x;
    float mn = INFINITY, mx = -INFINITY, sm = 0.f;
#pragma unroll
    for (int j = 0; j < PCHUNK; ++j){
        size_t o = ((size_t)b * PCHUNK + j) * CCH + c;
        mn = fminf(mn, part[o]);
        mx = fmaxf(mx, part[S1 + o]);
        sm += part[2 * (size_t)S1 + o];
    }
    int cnt = gptr[b + 1] - gptr[b];
    float mean = sm / fmaxf((float)cnt, 1.0f);
    if (cnt == 0){ mn = 0.f; mx = 0.f; }
    gbuf[b * 4 * CCH + 0 * CCH + c] = mn;
    gbuf[b * 4 * CCH + 1 * CCH + c] = mx;
    gbuf[b * 4 * CCH + 2 * CCH + c] = mean;
    gbuf[b * 4 * CCH + 3 * CCH + c] = sm;
}

// ---------------- head: gelu(g) @ head_W + head_b ----------------
__global__ __launch_bounds__(128) void head_k(const float* __restrict__ gbuf,
                                              const float* __restrict__ head_W,
                                              const float* __restrict__ head_b,
                                              float* __restrict__ out){
    __shared__ float gs[4 * CCH];
    int b = blockIdx.x;
    int o = threadIdx.x;
    for (int k = o; k < 4 * CCH; k += 128) gs[k] = gelu_f(gbuf[b * 4 * CCH + k]);
    __syncthreads();
    float acc = head_b[o];
    for (int k = 0; k < 4 * CCH; ++k) acc += gs[k] * head_W[k * NOUTP + o];
    out[b * NOUTP + o] = acc;
}

extern "C" void kernel_launch(void* const* d_in, const int* in_sizes, int n_in,
                              void* d_out, int out_size, void* d_ws, size_t ws_size,
                              hipStream_t stream){
    const float* x        = (const float*)d_in[0];
    const int*   ei       = (const int*)  d_in[1];
    const int*   batch    = (const int*)  d_in[2];
    const float* W0       = (const float*)d_in[3];
    const float* a_src0   = (const float*)d_in[4];
    const float* a_dst0   = (const float*)d_in[5];
    const float* b0       = (const float*)d_in[6];
    const float* Ws       = (const float*)d_in[7];
    const float* a_srcs   = (const float*)d_in[8];
    const float* a_dsts   = (const float*)d_in[9];
    const float* bs       = (const float*)d_in[10];
    const float* head_W   = (const float*)d_in[11];
    const float* head_b   = (const float*)d_in[12];
    float* out = (float*)d_out;

    char* p = (char*)d_ws;
    float* buf0 = (float*)p;            p += (size_t)NN * CCH * 4;
    float* buf1 = (float*)p;            p += (size_t)NN * CCH * 4;
    float* asb  = (float*)p;            p += (size_t)NN * HHH * 4;
    float* adb  = (float*)p;            p += (size_t)NN * HHH * 4;
    int* row_ptr = (int*)p;             p += 120016;               // (N+1)*4 padded
    int* cnt     = (int*)p;             p += (size_t)NN * 4;
    int* csr_src = (int*)p;             p += (size_t)ETOT * 4;
    float* gbuf  = (float*)p;           p += (size_t)BB * 4 * CCH * 4;
    int* gptr    = (int*)p;             p += 208;
    unsigned short* wthi = (unsigned short*)p; p += (size_t)(NLAY - 1) * CCH * CCH * 2;
    unsigned short* wtlo = (unsigned short*)p; p += (size_t)(NLAY - 1) * CCH * CCH * 2;

    // ---- CSR build + weight prep ----
    hipMemsetAsync(cnt, 0, (size_t)NN * 4, stream);
    count_k<<<(ETOT + 255) / 256, 256, 0, stream>>>(ei, cnt);
    scan_k<<<1, 1024, 0, stream>>>(cnt, row_ptr);
    hipMemsetAsync(cnt, 0, (size_t)NN * 4, stream);
    scatter_k<<<(ETOT + 255) / 256, 256, 0, stream>>>(ei, row_ptr, cnt, csr_src);
    gptr_k<<<(NN + 255) / 256, 256, 0, stream>>>(batch, gptr);
    wconv_k<<<dim3(NLAY - 1, 8), 256, 0, stream>>>(Ws, wthi, wtlo);

    // ---- layer 0 ----
    gemm_l0<<<NN, 256, 0, stream>>>(x, W0, buf1);
    alpha_k<<<(NN * HHH + 255) / 256, 256, 0, stream>>>(buf1, a_src0, a_dst0, asb, adb);
    agg_k<<<NN / 4, 256, 0, stream>>>(buf1, asb, adb, b0, row_ptr, csr_src, buf0);

    // ---- layers 1..9 ----
    dim3 ggrid(2, (NN + 127) / 128);
    for (int l = 1; l < NLAY; ++l){
        const unsigned short* whl = wthi + (size_t)(l - 1) * CCH * CCH;
        const unsigned short* wll = wtlo + (size_t)(l - 1) * CCH * CCH;
        const float* asl = a_srcs + (size_t)(l - 1) * HHH * DDD;
        const float* adl = a_dsts + (size_t)(l - 1) * HHH * DDD;
        const float* bl  = bs     + (size_t)(l - 1) * CCH;
        gemm_mfma<<<ggrid, 256, 0, stream>>>(buf0, whl, wll, buf1);
        alpha_k<<<(NN * HHH + 255) / 256, 256, 0, stream>>>(buf1, asl, adl, asb, adb);
        agg_k<<<NN / 4, 256, 0, stream>>>(buf1, asb, adb, bl, row_ptr, csr_src, buf0);
    }

    // ---- readout ----
    dim3 pgrid(BB, PCHUNK);
    pool1_k<<<pgrid, 256, 0, stream>>>(buf0, gptr, buf1);
    pool2_k<<<BB, 256, 0, stream>>>(buf1, gptr, gbuf);
    head_k<<<BB, 128, 0, stream>>>(gbuf, head_W, head_b, out);
}

// Round 5
// 1415.098 us; speedup vs baseline: 1.6722x; 1.0532x over previous
//
#include <hip/hip_runtime.h>
#include <math.h>

#define NN   30000
#define EE   480000
#define ETOT 510000   // EE + NN self loops
#define BB   48
#define HHH  4
#define DDD  64
#define CCH  256      // HHH*DDD
#define NINP 8
#define NOUTP 128
#define NLAY 10
#define SLOPE 0.2f
#define PCHUNK 32     // pool stage-1 chunks per graph

typedef short v8s  __attribute__((ext_vector_type(8)));
typedef float v4f  __attribute__((ext_vector_type(4)));

__device__ __forceinline__ float gelu_f(float x){
    return 0.5f * x * (1.0f + erff(x * 0.70710678118654752f));
}
__device__ __forceinline__ unsigned short f2bf(float f){
    unsigned u = __float_as_uint(f);
    unsigned r = u + 0x7FFF + ((u >> 16) & 1);   // RNE
    return (unsigned short)(r >> 16);
}
__device__ __forceinline__ float bf2f(unsigned short b){
    return __uint_as_float(((unsigned)b) << 16);
}
__device__ __forceinline__ float lrelu(float e){
    return (e > 0.f) ? e : SLOPE * e;
}

// ---------------- CSR build ----------------
__global__ void count_k(const int* __restrict__ ei, int* __restrict__ cnt){
    int e = blockIdx.x * 256 + threadIdx.x;
    if (e >= ETOT) return;
    int d = (e < EE) ? ei[EE + e] : (e - EE);
    atomicAdd(&cnt[d], 1);
}

__global__ __launch_bounds__(1024) void scan_k(const int* __restrict__ cnt, int* __restrict__ row_ptr){
    __shared__ int sdata[1024];
    __shared__ int carry;
    int tid = threadIdx.x;
    if (tid == 0) carry = 0;
    __syncthreads();
    for (int base = 0; base < NN; base += 1024){
        int i = base + tid;
        int v = (i < NN) ? cnt[i] : 0;
        sdata[tid] = v;
        __syncthreads();
        for (int off = 1; off < 1024; off <<= 1){
            int t = (tid >= off) ? sdata[tid - off] : 0;
            __syncthreads();
            sdata[tid] += t;
            __syncthreads();
        }
        if (i < NN) row_ptr[i] = carry + sdata[tid] - v;   // exclusive
        __syncthreads();
        if (tid == 1023) carry += sdata[1023];
        __syncthreads();
    }
    if (tid == 0) row_ptr[NN] = carry;
}

__global__ void scatter_k(const int* __restrict__ ei, const int* __restrict__ row_ptr,
                          int* __restrict__ cursor, int* __restrict__ csr_src){
    int e = blockIdx.x * 256 + threadIdx.x;
    if (e >= ETOT) return;
    int s, d;
    if (e < EE){ s = ei[e]; d = ei[EE + e]; } else { s = d = e - EE; }
    int pos = row_ptr[d] + atomicAdd(&cursor[d], 1);
    csr_src[pos] = s;
}

// ---------------- weight prep: transpose + split to bf16 hi/lo ----------------
__global__ __launch_bounds__(256) void wconv_k(const float* __restrict__ Ws,
                                               unsigned short* __restrict__ WT_hi,
                                               unsigned short* __restrict__ WT_lo){
    int l = blockIdx.x;
    int n = threadIdx.x;
    int k0 = blockIdx.y * 32;
    const float* W = Ws + (size_t)l * CCH * CCH;
    unsigned short* th = WT_hi + (size_t)l * CCH * CCH;
    unsigned short* tl = WT_lo + (size_t)l * CCH * CCH;
    for (int k = k0; k < k0 + 32; ++k){
        float w = W[k * CCH + n];
        unsigned short h = f2bf(w);
        th[n * CCH + k] = h;
        tl[n * CCH + k] = f2bf(w - bf2f(h));
    }
}

// ---------------- alpha-weight prep: wa[j][k] = sum_d W[k][j*64+d]*a[j][d] ----------------
// j 0..3 = a_src heads, j 4..7 = a_dst heads, j 8..15 = zero padding (16-col tile).
__global__ __launch_bounds__(256) void waconv_k(const float* __restrict__ Ws,
                                                const float* __restrict__ a_srcs,
                                                const float* __restrict__ a_dsts,
                                                unsigned short* __restrict__ wa_hi,
                                                unsigned short* __restrict__ wa_lo){
    int l = blockIdx.x;
    int k = threadIdx.x;
    const float* W = Ws + (size_t)l * CCH * CCH;
#pragma unroll
    for (int j = 0; j < 8; ++j){
        const float* av = (j < 4) ? (a_srcs + (size_t)l * CCH + j * DDD)
                                  : (a_dsts + (size_t)l * CCH + (j - 4) * DDD);
        int cb = (j & 3) * DDD;
        float s = 0.f;
        for (int d = 0; d < DDD; ++d) s += W[k * CCH + cb + d] * av[d];
        unsigned short hb = f2bf(s);
        wa_hi[((size_t)l * 16 + j) * CCH + k] = hb;
        wa_lo[((size_t)l * 16 + j) * CCH + k] = f2bf(s - bf2f(hb));
    }
#pragma unroll
    for (int j = 8; j < 16; ++j){
        wa_hi[((size_t)l * 16 + j) * CCH + k] = 0;
        wa_lo[((size_t)l * 16 + j) * CCH + k] = 0;
    }
}

// ---------------- layer 0 GEMM: [N,8] @ [8,256] ----------------
__global__ __launch_bounds__(256) void gemm_l0(const float* __restrict__ x,
                                               const float* __restrict__ W0,
                                               float* __restrict__ out){
    __shared__ float xs[NINP];
    int n = blockIdx.x;
    int c = threadIdx.x;
    if (c < NINP) xs[c] = x[n * NINP + c];
    __syncthreads();
    float acc = 0.f;
#pragma unroll
    for (int k = 0; k < NINP; ++k) acc += xs[k] * W0[k * CCH + c];
    out[n * CCH + c] = acc;
}

// ---------------- main GEMM: gelu(A) @ W via split-bf16 MFMA, fused alpha ----------------
// Blocks with blockIdx.x==0, waves wc==0 additionally accumulate one extra
// B column-tile (the precomputed W·a_src / W·a_dst projections) and store
// cols 0..7 of it to asb/adb -- replaces the standalone alpha_k pass.
__global__ __launch_bounds__(256) void gemm_mfma(const float* __restrict__ A,
                                                 const unsigned short* __restrict__ Bhi,
                                                 const unsigned short* __restrict__ Blo,
                                                 const unsigned short* __restrict__ WAhi,
                                                 const unsigned short* __restrict__ WAlo,
                                                 float* __restrict__ C,
                                                 float* __restrict__ asb,
                                                 float* __restrict__ adb){
    int tid  = threadIdx.x;
    int lane = tid & 63, wave = tid >> 6;
    int wr = wave >> 1, wc = wave & 1;
    int rowBase = blockIdx.y * 128 + wr * 64;
    int colBase = blockIdx.x * 128 + wc * 64;
    int fr = lane & 15;      // fragment row (A) / col (B,D)
    int kg = lane >> 4;      // k-group 0..3
    bool doAlpha = (blockIdx.x == 0) && (wc == 0);

    v4f acc[4][4];
#pragma unroll
    for (int mi = 0; mi < 4; ++mi)
#pragma unroll
        for (int ni = 0; ni < 4; ++ni) acc[mi][ni] = (v4f){0.f, 0.f, 0.f, 0.f};
    v4f acca[4];
#pragma unroll
    for (int mi = 0; mi < 4; ++mi) acca[mi] = (v4f){0.f, 0.f, 0.f, 0.f};

    const float* aptr[4];
#pragma unroll
    for (int mi = 0; mi < 4; ++mi){
        int r = rowBase + mi * 16 + fr;
        if (r >= NN) r = NN - 1;                  // clamp; stores guarded below
        aptr[mi] = A + (size_t)r * CCH + kg * 8;
    }
    const unsigned short* bhp[4];
    const unsigned short* blp[4];
#pragma unroll
    for (int ni = 0; ni < 4; ++ni){
        int c = colBase + ni * 16 + fr;
        bhp[ni] = Bhi + (size_t)c * CCH + kg * 8;
        blp[ni] = Blo + (size_t)c * CCH + kg * 8;
    }
    const unsigned short* wahp = WAhi + (size_t)fr * CCH + kg * 8;
    const unsigned short* walp = WAlo + (size_t)fr * CCH + kg * 8;

    for (int kc = 0; kc < CCH; kc += 32){
        v8s ah[4], al[4], bh[4], bl[4];
#pragma unroll
        for (int mi = 0; mi < 4; ++mi){
            float4 v0 = *(const float4*)(aptr[mi] + kc);
            float4 v1 = *(const float4*)(aptr[mi] + kc + 4);
            float f[8] = {v0.x, v0.y, v0.z, v0.w, v1.x, v1.y, v1.z, v1.w};
            v8s hi, lo;
#pragma unroll
            for (int j = 0; j < 8; ++j){
                float g = gelu_f(f[j]);
                unsigned short hb = f2bf(g);
                hi[j] = (short)hb;
                lo[j] = (short)f2bf(g - bf2f(hb));
            }
            ah[mi] = hi; al[mi] = lo;
        }
#pragma unroll
        for (int ni = 0; ni < 4; ++ni){
            bh[ni] = *(const v8s*)(bhp[ni] + kc);
            bl[ni] = *(const v8s*)(blp[ni] + kc);
        }
#pragma unroll
        for (int mi = 0; mi < 4; ++mi)
#pragma unroll
            for (int ni = 0; ni < 4; ++ni){
                acc[mi][ni] = __builtin_amdgcn_mfma_f32_16x16x32_bf16(ah[mi], bh[ni], acc[mi][ni], 0, 0, 0);
                acc[mi][ni] = __builtin_amdgcn_mfma_f32_16x16x32_bf16(al[mi], bh[ni], acc[mi][ni], 0, 0, 0);
                acc[mi][ni] = __builtin_amdgcn_mfma_f32_16x16x32_bf16(ah[mi], bl[ni], acc[mi][ni], 0, 0, 0);
            }
        if (doAlpha){
            v8s wh = *(const v8s*)(wahp + kc);
            v8s wl = *(const v8s*)(walp + kc);
#pragma unroll
            for (int mi = 0; mi < 4; ++mi){
                acca[mi] = __builtin_amdgcn_mfma_f32_16x16x32_bf16(ah[mi], wh, acca[mi], 0, 0, 0);
                acca[mi] = __builtin_amdgcn_mfma_f32_16x16x32_bf16(al[mi], wh, acca[mi], 0, 0, 0);
                acca[mi] = __builtin_amdgcn_mfma_f32_16x16x32_bf16(ah[mi], wl, acca[mi], 0, 0, 0);
            }
        }
    }

    // D layout: col = lane&15 (=fr), row = (lane>>4)*4 + j (=kg*4+j)
#pragma unroll
    for (int mi = 0; mi < 4; ++mi)
#pragma unroll
        for (int j = 0; j < 4; ++j){
            int r = rowBase + mi * 16 + kg * 4 + j;
            if (r < NN){
#pragma unroll
                for (int ni = 0; ni < 4; ++ni)
                    C[(size_t)r * CCH + colBase + ni * 16 + fr] = acc[mi][ni][j];
            }
        }
    if (doAlpha){
#pragma unroll
        for (int mi = 0; mi < 4; ++mi)
#pragma unroll
            for (int j = 0; j < 4; ++j){
                int r = rowBase + mi * 16 + kg * 4 + j;
                if (r < NN){
                    float val = acca[mi][j];
                    if (fr < 4)      asb[(size_t)r * HHH + fr]       = val;
                    else if (fr < 8) adb[(size_t)r * HHH + (fr - 4)] = val;
                }
            }
    }
}

// ---------------- alpha projections (layer 0 only) ----------------
__global__ void alpha_k(const float* __restrict__ h,
                        const float* __restrict__ a_src, const float* __restrict__ a_dst,
                        float* __restrict__ as_out, float* __restrict__ ad_out){
    int t = blockIdx.x * 256 + threadIdx.x;
    if (t >= NN * HHH) return;
    int n = t >> 2, hh = t & 3;
    const float4* hp = (const float4*)(h + (size_t)n * CCH + hh * DDD);
    const float4* sp = (const float4*)(a_src + hh * DDD);
    const float4* dp = (const float4*)(a_dst + hh * DDD);
    float s1 = 0.f, s2 = 0.f;
#pragma unroll
    for (int q = 0; q < DDD / 4; ++q){
        float4 hv = hp[q], sv = sp[q], dv = dp[q];
        s1 += hv.x * sv.x + hv.y * sv.y + hv.z * sv.z + hv.w * sv.w;
        s2 += hv.x * dv.x + hv.y * dv.y + hv.z * dv.z + hv.w * dv.w;
    }
    as_out[t] = s1;
    ad_out[t] = s2;
}

// ---------------- per-node softmax + aggregation: ONE WAVE PER NODE ----------------
// Gather is software-pipelined: 2-slot double-buffer over groups of 4 rows in
// named registers -> steady-state 8 outstanding 1KB row gathers per wave.
#define LOADG(gg, V0, V1, V2, V3, A0, A1, A2, A3)                      \
    { int _b = (gg) << 2;                                              \
      int _i0 = ix_w[_b], _i1 = ix_w[_b + 1];                          \
      int _i2 = ix_w[_b + 2], _i3 = ix_w[_b + 3];                      \
      A0 = al_w[(_b + 0) * HHH + hc];                                  \
      A1 = al_w[(_b + 1) * HHH + hc];                                  \
      A2 = al_w[(_b + 2) * HHH + hc];                                  \
      A3 = al_w[(_b + 3) * HHH + hc];                                  \
      V0 = *(const float4*)(h + (size_t)_i0 * CCH + coff);             \
      V1 = *(const float4*)(h + (size_t)_i1 * CCH + coff);             \
      V2 = *(const float4*)(h + (size_t)_i2 * CCH + coff);             \
      V3 = *(const float4*)(h + (size_t)_i3 * CCH + coff); }

#define CONSUME(V0, V1, V2, V3, A0, A1, A2, A3)                        \
    { acc.x += V0.x * A0 + V1.x * A1 + V2.x * A2 + V3.x * A3;          \
      acc.y += V0.y * A0 + V1.y * A1 + V2.y * A2 + V3.y * A3;          \
      acc.z += V0.z * A0 + V1.z * A1 + V2.z * A2 + V3.z * A3;          \
      acc.w += V0.w * A0 + V1.w * A1 + V2.w * A2 + V3.w * A3; }

__global__ __launch_bounds__(256) void agg_k(const float* __restrict__ h,
                                             const float* __restrict__ asrc,
                                             const float* __restrict__ adst,
                                             const float* __restrict__ bias,
                                             const int* __restrict__ row_ptr,
                                             const int* __restrict__ csr_src,
                                             float* __restrict__ out){
    __shared__ float s_al[4][64 * HHH];
    __shared__ int   s_ix[4][64];

    int wave = threadIdx.x >> 6, lane = threadIdx.x & 63;
    int n = blockIdx.x * 4 + wave;
    int row0 = row_ptr[n];
    int deg  = row_ptr[n + 1] - row0;
    float4 ad = *(const float4*)(adst + (size_t)n * HHH);
    int coff = lane << 2;        // this lane's 4 channels
    int hc   = lane >> 4;        // head those channels belong to
    float* al_w = s_al[wave];
    int*   ix_w = s_ix[wave];
    float4 acc = make_float4(0.f, 0.f, 0.f, 0.f);

    if (deg <= 64){
        // ---- fast path: lane k = edge k ----
        int k = lane;
        int s = 0;
        float e0 = -INFINITY, e1 = -INFINITY, e2 = -INFINITY, e3 = -INFINITY;
        if (k < deg){
            s = csr_src[row0 + k];
            float4 as = *(const float4*)(asrc + (size_t)s * HHH);
            e0 = lrelu(as.x + ad.x); e1 = lrelu(as.y + ad.y);
            e2 = lrelu(as.z + ad.z); e3 = lrelu(as.w + ad.w);
        }
        float m0 = e0, m1 = e1, m2 = e2, m3 = e3;
#pragma unroll
        for (int off = 32; off; off >>= 1){
            m0 = fmaxf(m0, __shfl_xor(m0, off));
            m1 = fmaxf(m1, __shfl_xor(m1, off));
            m2 = fmaxf(m2, __shfl_xor(m2, off));
            m3 = fmaxf(m3, __shfl_xor(m3, off));
        }
        float x0 = 0.f, x1 = 0.f, x2 = 0.f, x3 = 0.f;
        if (k < deg){
            x0 = __expf(e0 - m0); x1 = __expf(e1 - m1);
            x2 = __expf(e2 - m2); x3 = __expf(e3 - m3);
        }
        float z0 = x0, z1 = x1, z2 = x2, z3 = x3;
#pragma unroll
        for (int off = 32; off; off >>= 1){
            z0 += __shfl_xor(z0, off);
            z1 += __shfl_xor(z1, off);
            z2 += __shfl_xor(z2, off);
            z3 += __shfl_xor(z3, off);
        }
        if (k < deg){
            float4 alv;
            alv.x = x0 / (z0 + 1e-16f);
            alv.y = x1 / (z1 + 1e-16f);
            alv.z = x2 / (z2 + 1e-16f);
            alv.w = x3 / (z3 + 1e-16f);
            ix_w[k] = s;
            *(float4*)&al_w[k * HHH] = alv;
        }
        // ---- pipelined gather: groups of 4 rows, 2-slot double-buffer ----
        int ng = deg >> 2;
        float4 vA0, vA1, vA2, vA3, vB0, vB1, vB2, vB3;
        float  aA0, aA1, aA2, aA3, aB0, aB1, aB2, aB3;
        if (ng > 0) LOADG(0, vA0, vA1, vA2, vA3, aA0, aA1, aA2, aA3);
        if (ng > 1) LOADG(1, vB0, vB1, vB2, vB3, aB0, aB1, aB2, aB3);
        for (int g = 0; g < ng; g += 2){
            if (g + 2 < ng) {
                CONSUME(vA0, vA1, vA2, vA3, aA0, aA1, aA2, aA3);
                LOADG(g + 2, vA0, vA1, vA2, vA3, aA0, aA1, aA2, aA3);
            } else {
                CONSUME(vA0, vA1, vA2, vA3, aA0, aA1, aA2, aA3);
            }
            if (g + 1 < ng){
                if (g + 3 < ng) {
                    CONSUME(vB0, vB1, vB2, vB3, aB0, aB1, aB2, aB3);
                    LOADG(g + 3, vB0, vB1, vB2, vB3, aB0, aB1, aB2, aB3);
                } else {
                    CONSUME(vB0, vB1, vB2, vB3, aB0, aB1, aB2, aB3);
                }
            }
        }
        for (int kk = ng << 2; kk < deg; ++kk){
            int i0 = ix_w[kk];
            float a0 = al_w[kk * HHH + hc];
            float4 v0 = *(const float4*)(h + (size_t)i0 * CCH + coff);
            acc.x += v0.x * a0; acc.y += v0.y * a0; acc.z += v0.z * a0; acc.w += v0.w * a0;
        }
    } else {
        // ---- generic path: online softmax over 64-edge chunks ----
        float m0 = -INFINITY, m1 = -INFINITY, m2 = -INFINITY, m3 = -INFINITY;
        float z0 = 0.f, z1 = 0.f, z2 = 0.f, z3 = 0.f;
        for (int c0 = 0; c0 < deg; c0 += 64){
            int k = c0 + lane;
            float e0 = -INFINITY, e1 = -INFINITY, e2 = -INFINITY, e3 = -INFINITY;
            if (k < deg){
                int s = csr_src[row0 + k];
                float4 as = *(const float4*)(asrc + (size_t)s * HHH);
                e0 = lrelu(as.x + ad.x); e1 = lrelu(as.y + ad.y);
                e2 = lrelu(as.z + ad.z); e3 = lrelu(as.w + ad.w);
            }
            float c0m = e0, c1m = e1, c2m = e2, c3m = e3;
#pragma unroll
            for (int off = 32; off; off >>= 1){
                c0m = fmaxf(c0m, __shfl_xor(c0m, off));
                c1m = fmaxf(c1m, __shfl_xor(c1m, off));
                c2m = fmaxf(c2m, __shfl_xor(c2m, off));
                c3m = fmaxf(c3m, __shfl_xor(c3m, off));
            }
            float n0 = fmaxf(m0, c0m), n1 = fmaxf(m1, c1m);
            float n2 = fmaxf(m2, c2m), n3 = fmaxf(m3, c3m);
            float x0 = 0.f, x1 = 0.f, x2 = 0.f, x3 = 0.f;
            if (k < deg){
                x0 = __expf(e0 - n0); x1 = __expf(e1 - n1);
                x2 = __expf(e2 - n2); x3 = __expf(e3 - n3);
            }
            float s0 = x0, s1 = x1, s2 = x2, s3 = x3;
#pragma unroll
            for (int off = 32; off; off >>= 1){
                s0 += __shfl_xor(s0, off);
                s1 += __shfl_xor(s1, off);
                s2 += __shfl_xor(s2, off);
                s3 += __shfl_xor(s3, off);
            }
            z0 = z0 * ((m0 == -INFINITY) ? 0.f : __expf(m0 - n0)) + s0;
            z1 = z1 * ((m1 == -INFINITY) ? 0.f : __expf(m1 - n1)) + s1;
            z2 = z2 * ((m2 == -INFINITY) ? 0.f : __expf(m2 - n2)) + s2;
            z3 = z3 * ((m3 == -INFINITY) ? 0.f : __expf(m3 - n3)) + s3;
            m0 = n0; m1 = n1; m2 = n2; m3 = n3;
        }
        float iz0 = 1.f / (z0 + 1e-16f), iz1 = 1.f / (z1 + 1e-16f);
        float iz2 = 1.f / (z2 + 1e-16f), iz3 = 1.f / (z3 + 1e-16f);
        for (int c0 = 0; c0 < deg; c0 += 64){
            int k = c0 + lane;
            if (k < deg){
                int s = csr_src[row0 + k];
                float4 as = *(const float4*)(asrc + (size_t)s * HHH);
                float4 alv;
                alv.x = __expf(lrelu(as.x + ad.x) - m0) * iz0;
                alv.y = __expf(lrelu(as.y + ad.y) - m1) * iz1;
                alv.z = __expf(lrelu(as.z + ad.z) - m2) * iz2;
                alv.w = __expf(lrelu(as.w + ad.w) - m3) * iz3;
                ix_w[lane] = s;
                *(float4*)&al_w[lane * HHH] = alv;
            }
            int cnt = deg - c0; if (cnt > 64) cnt = 64;
            for (int j = 0; j < cnt; ++j){
                int i0 = ix_w[j];
                float a0 = al_w[j * HHH + hc];
                float4 v0 = *(const float4*)(h + (size_t)i0 * CCH + coff);
                acc.x += v0.x * a0; acc.y += v0.y * a0; acc.z += v0.z * a0; acc.w += v0.w * a0;
            }
        }
    }

    float4 bv = *(const float4*)(bias + coff);
    acc.x += bv.x; acc.y += bv.y; acc.z += bv.z; acc.w += bv.w;
    *(float4*)(out + (size_t)n * CCH + coff) = acc;
}

// ---------------- graph boundary pointers (batch is sorted) ----------------
__global__ void gptr_k(const int* __restrict__ batch, int* __restrict__ gptr){
    int i = blockIdx.x * 256 + threadIdx.x;
    if (i >= NN) return;
    int bi = batch[i];
    int bp = (i == 0) ? -1 : batch[i - 1];
    for (int g = bp + 1; g <= bi; ++g) gptr[g] = i;
    if (i == NN - 1){
        for (int g = bi + 1; g <= BB; ++g) gptr[g] = NN;
    }
}

// ---------------- pooling stage 1 ----------------
__global__ __launch_bounds__(256) void pool1_k(const float* __restrict__ h,
                                               const int* __restrict__ gptr,
                                               float* __restrict__ part){
    const int S1 = BB * PCHUNK * CCH;
    int b = blockIdx.x, j = blockIdx.y, c = threadIdx.x;
    int s = gptr[b], e = gptr[b + 1];
    int len = e - s;
    int per = (len + PCHUNK - 1) / PCHUNK;
    int r0 = s + j * per;
    int r1 = r0 + per; if (r1 > e) r1 = e;
    float mn = INFINITY, mx = -INFINITY, sm = 0.f;
    int n = r0;
    for (; n + 4 <= r1; n += 4){
        float v0 = h[(size_t)(n + 0) * CCH + c];
        float v1 = h[(size_t)(n + 1) * CCH + c];
        float v2 = h[(size_t)(n + 2) * CCH + c];
        float v3 = h[(size_t)(n + 3) * CCH + c];
        mn = fminf(mn, fminf(fminf(v0, v1), fminf(v2, v3)));
        mx = fmaxf(mx, fmaxf(fmaxf(v0, v1), fmaxf(v2, v3)));
        sm += (v0 + v1) + (v2 + v3);
    }
    for (; n < r1; ++n){
        float v = h[(size_t)n * CCH + c];
        mn = fminf(mn, v); mx = fmaxf(mx, v); sm += v;
    }
    size_t o = ((size_t)b * PCHUNK + j) * CCH + c;
    part[o] = mn; part[S1 + o] = mx; part[2 * (size_t)S1 + o] = sm;
}

// ---------------- pooling stage 2 ----------------
__global__ __launch_bounds__(256) void pool2_k(const float* __restrict__ part,
                                               const int* __restrict__ gptr,
                                               float* __restrict__ gbuf){
    const int S1 = BB * PCHUNK * CCH;
    int b = blockIdx.x, c = threadIdx.x;
    float mn = INFINITY, mx = -INFINITY, sm = 0.f;
#pragma unroll
    for (int j = 0; j < PCHUNK; ++j){
        size_t o = ((size_t)b * PCHUNK + j) * CCH + c;
        mn = fminf(mn, part[o]);
        mx = fmaxf(mx, part[S1 + o]);
        sm += part[2 * (size_t)S1 + o];
    }
    int cnt = gptr[b + 1] - gptr[b];
    float mean = sm / fmaxf((float)cnt, 1.0f);
    if (cnt == 0){ mn = 0.f; mx = 0.f; }
    gbuf[b * 4 * CCH + 0 * CCH + c] = mn;
    gbuf[b * 4 * CCH + 1 * CCH + c] = mx;
    gbuf[b * 4 * CCH + 2 * CCH + c] = mean;
    gbuf[b * 4 * CCH + 3 * CCH + c] = sm;
}

// ---------------- head: gelu(g) @ head_W + head_b ----------------
__global__ __launch_bounds__(128) void head_k(const float* __restrict__ gbuf,
                                              const float* __restrict__ head_W,
                                              const float* __restrict__ head_b,
                                              float* __restrict__ out){
    __shared__ float gs[4 * CCH];
    int b = blockIdx.x;
    int o = threadIdx.x;
    for (int k = o; k < 4 * CCH; k += 128) gs[k] = gelu_f(gbuf[b * 4 * CCH + k]);
    __syncthreads();
    float acc = head_b[o];
    for (int k = 0; k < 4 * CCH; ++k) acc += gs[k] * head_W[k * NOUTP + o];
    out[b * NOUTP + o] = acc;
}

extern "C" void kernel_launch(void* const* d_in, const int* in_sizes, int n_in,
                              void* d_out, int out_size, void* d_ws, size_t ws_size,
                              hipStream_t stream){
    const float* x        = (const float*)d_in[0];
    const int*   ei       = (const int*)  d_in[1];
    const int*   batch    = (const int*)  d_in[2];
    const float* W0       = (const float*)d_in[3];
    const float* a_src0   = (const float*)d_in[4];
    const float* a_dst0   = (const float*)d_in[5];
    const float* b0       = (const float*)d_in[6];
    const float* Ws       = (const float*)d_in[7];
    const float* a_srcs   = (const float*)d_in[8];
    const float* a_dsts   = (const float*)d_in[9];
    const float* bs       = (const float*)d_in[10];
    const float* head_W   = (const float*)d_in[11];
    const float* head_b   = (const float*)d_in[12];
    float* out = (float*)d_out;

    char* p = (char*)d_ws;
    float* buf0 = (float*)p;            p += (size_t)NN * CCH * 4;
    float* buf1 = (float*)p;            p += (size_t)NN * CCH * 4;
    float* asb  = (float*)p;            p += (size_t)NN * HHH * 4;
    float* adb  = (float*)p;            p += (size_t)NN * HHH * 4;
    int* row_ptr = (int*)p;             p += 120016;               // (N+1)*4 padded
    int* cnt     = (int*)p;             p += (size_t)NN * 4;
    int* csr_src = (int*)p;             p += (size_t)ETOT * 4;
    float* gbuf  = (float*)p;           p += (size_t)BB * 4 * CCH * 4;
    int* gptr    = (int*)p;             p += 208;
    unsigned short* wthi = (unsigned short*)p; p += (size_t)(NLAY - 1) * CCH * CCH * 2;
    unsigned short* wtlo = (unsigned short*)p; p += (size_t)(NLAY - 1) * CCH * CCH * 2;
    unsigned short* wahi = (unsigned short*)p; p += (size_t)(NLAY - 1) * 16 * CCH * 2;
    unsigned short* walo = (unsigned short*)p; p += (size_t)(NLAY - 1) * 16 * CCH * 2;

    // ---- CSR build + weight prep ----
    hipMemsetAsync(cnt, 0, (size_t)NN * 4, stream);
    count_k<<<(ETOT + 255) / 256, 256, 0, stream>>>(ei, cnt);
    scan_k<<<1, 1024, 0, stream>>>(cnt, row_ptr);
    hipMemsetAsync(cnt, 0, (size_t)NN * 4, stream);
    scatter_k<<<(ETOT + 255) / 256, 256, 0, stream>>>(ei, row_ptr, cnt, csr_src);
    gptr_k<<<(NN + 255) / 256, 256, 0, stream>>>(batch, gptr);
    wconv_k<<<dim3(NLAY - 1, 8), 256, 0, stream>>>(Ws, wthi, wtlo);
    waconv_k<<<NLAY - 1, 256, 0, stream>>>(Ws, a_srcs, a_dsts, wahi, walo);

    // ---- layer 0 ----
    gemm_l0<<<NN, 256, 0, stream>>>(x, W0, buf1);
    alpha_k<<<(NN * HHH + 255) / 256, 256, 0, stream>>>(buf1, a_src0, a_dst0, asb, adb);
    agg_k<<<NN / 4, 256, 0, stream>>>(buf1, asb, adb, b0, row_ptr, csr_src, buf0);

    // ---- layers 1..9 (alpha fused into gemm) ----
    dim3 ggrid(2, (NN + 127) / 128);
    for (int l = 1; l < NLAY; ++l){
        const unsigned short* whl = wthi + (size_t)(l - 1) * CCH * CCH;
        const unsigned short* wll = wtlo + (size_t)(l - 1) * CCH * CCH;
        const unsigned short* wal_h = wahi + (size_t)(l - 1) * 16 * CCH;
        const unsigned short* wal_l = walo + (size_t)(l - 1) * 16 * CCH;
        const float* bl  = bs + (size_t)(l - 1) * CCH;
        gemm_mfma<<<ggrid, 256, 0, stream>>>(buf0, whl, wll, wal_h, wal_l, buf1, asb, adb);
        agg_k<<<NN / 4, 256, 0, stream>>>(buf1, asb, adb, bl, row_ptr, csr_src, buf0);
    }

    // ---- readout ----
    dim3 pgrid(BB, PCHUNK);
    pool1_k<<<pgrid, 256, 0, stream>>>(buf0, gptr, buf1);
    pool2_k<<<BB, 256, 0, stream>>>(buf1, gptr, gbuf);
    head_k<<<BB, 128, 0, stream>>>(gbuf, head_W, head_b, out);
}

// Round 6
// 1119.768 us; speedup vs baseline: 2.1133x; 1.2637x over previous
//
#include <hip/hip_runtime.h>
#include <math.h>

#define NN   30000
#define EE   480000
#define ETOT 510000   // EE + NN self loops
#define BB   48
#define HHH  4
#define DDD  64
#define CCH  256      // HHH*DDD
#define NINP 8
#define NOUTP 128
#define NLAY 10
#define SLOPE 0.2f
#define PCHUNK 32     // pool stage-1 chunks per graph

typedef short v8s  __attribute__((ext_vector_type(8)));
typedef float v4f  __attribute__((ext_vector_type(4)));

__device__ __forceinline__ float gelu_f(float x){
    return 0.5f * x * (1.0f + erff(x * 0.70710678118654752f));
}
__device__ __forceinline__ unsigned short f2bf(float f){
    unsigned u = __float_as_uint(f);
    unsigned r = u + 0x7FFF + ((u >> 16) & 1);   // RNE
    return (unsigned short)(r >> 16);
}
__device__ __forceinline__ float bf2f(unsigned short b){
    return __uint_as_float(((unsigned)b) << 16);
}
__device__ __forceinline__ float lrelu(float e){
    return (e > 0.f) ? e : SLOPE * e;
}
// unpack 4 bf16 (stored little-endian in uint2) -> float4
__device__ __forceinline__ float4 up4(uint2 u){
    float4 r;
    r.x = __uint_as_float(u.x << 16);
    r.y = __uint_as_float(u.x & 0xFFFF0000u);
    r.z = __uint_as_float(u.y << 16);
    r.w = __uint_as_float(u.y & 0xFFFF0000u);
    return r;
}

// ---------------- CSR build ----------------
__global__ void count_k(const int* __restrict__ ei, int* __restrict__ cnt){
    int e = blockIdx.x * 256 + threadIdx.x;
    if (e >= ETOT) return;
    int d = (e < EE) ? ei[EE + e] : (e - EE);
    atomicAdd(&cnt[d], 1);
}

__global__ __launch_bounds__(1024) void scan_k(const int* __restrict__ cnt, int* __restrict__ row_ptr){
    __shared__ int sdata[1024];
    __shared__ int carry;
    int tid = threadIdx.x;
    if (tid == 0) carry = 0;
    __syncthreads();
    for (int base = 0; base < NN; base += 1024){
        int i = base + tid;
        int v = (i < NN) ? cnt[i] : 0;
        sdata[tid] = v;
        __syncthreads();
        for (int off = 1; off < 1024; off <<= 1){
            int t = (tid >= off) ? sdata[tid - off] : 0;
            __syncthreads();
            sdata[tid] += t;
            __syncthreads();
        }
        if (i < NN) row_ptr[i] = carry + sdata[tid] - v;   // exclusive
        __syncthreads();
        if (tid == 1023) carry += sdata[1023];
        __syncthreads();
    }
    if (tid == 0) row_ptr[NN] = carry;
}

__global__ void scatter_k(const int* __restrict__ ei, const int* __restrict__ row_ptr,
                          int* __restrict__ cursor, int* __restrict__ csr_src){
    int e = blockIdx.x * 256 + threadIdx.x;
    if (e >= ETOT) return;
    int s, d;
    if (e < EE){ s = ei[e]; d = ei[EE + e]; } else { s = d = e - EE; }
    int pos = row_ptr[d] + atomicAdd(&cursor[d], 1);
    csr_src[pos] = s;
}

// ---------------- weight prep: transpose + split to bf16 hi/lo ----------------
__global__ __launch_bounds__(256) void wconv_k(const float* __restrict__ Ws,
                                               unsigned short* __restrict__ WT_hi,
                                               unsigned short* __restrict__ WT_lo){
    int l = blockIdx.x;
    int n = threadIdx.x;
    int k0 = blockIdx.y * 32;
    const float* W = Ws + (size_t)l * CCH * CCH;
    unsigned short* th = WT_hi + (size_t)l * CCH * CCH;
    unsigned short* tl = WT_lo + (size_t)l * CCH * CCH;
    for (int k = k0; k < k0 + 32; ++k){
        float w = W[k * CCH + n];
        unsigned short h = f2bf(w);
        th[n * CCH + k] = h;
        tl[n * CCH + k] = f2bf(w - bf2f(h));
    }
}

// ---------------- alpha-weight prep: wa[j][k] = sum_d W[k][j*64+d]*a[j][d] ----------------
__global__ __launch_bounds__(256) void waconv_k(const float* __restrict__ Ws,
                                                const float* __restrict__ a_srcs,
                                                const float* __restrict__ a_dsts,
                                                unsigned short* __restrict__ wa_hi,
                                                unsigned short* __restrict__ wa_lo){
    int l = blockIdx.x;
    int k = threadIdx.x;
    const float* W = Ws + (size_t)l * CCH * CCH;
#pragma unroll
    for (int j = 0; j < 8; ++j){
        const float* av = (j < 4) ? (a_srcs + (size_t)l * CCH + j * DDD)
                                  : (a_dsts + (size_t)l * CCH + (j - 4) * DDD);
        int cb = (j & 3) * DDD;
        float s = 0.f;
        for (int d = 0; d < DDD; ++d) s += W[k * CCH + cb + d] * av[d];
        unsigned short hb = f2bf(s);
        wa_hi[((size_t)l * 16 + j) * CCH + k] = hb;
        wa_lo[((size_t)l * 16 + j) * CCH + k] = f2bf(s - bf2f(hb));
    }
#pragma unroll
    for (int j = 8; j < 16; ++j){
        wa_hi[((size_t)l * 16 + j) * CCH + k] = 0;
        wa_lo[((size_t)l * 16 + j) * CCH + k] = 0;
    }
}

// ---------------- layer 0 fused: h0 = x@W0 (bf16 out) + alpha projections ----------------
__global__ __launch_bounds__(256) void l0_fused(const float* __restrict__ x,
                                                const float* __restrict__ W0,
                                                const float* __restrict__ a_src,
                                                const float* __restrict__ a_dst,
                                                unsigned short* __restrict__ hout,
                                                float* __restrict__ asb,
                                                float* __restrict__ adb){
    __shared__ float xs[NINP];
    int n = blockIdx.x;
    int c = threadIdx.x;
    if (c < NINP) xs[c] = x[n * NINP + c];
    __syncthreads();
    float acc = 0.f;
#pragma unroll
    for (int k = 0; k < NINP; ++k) acc += xs[k] * W0[k * CCH + c];
    hout[(size_t)n * CCH + c] = f2bf(acc);
    // alpha: wave hh == head hh (channels hh*64..hh*64+63)
    int hh = c >> 6, lane = c & 63;
    float s1 = acc * a_src[hh * DDD + lane];
    float s2 = acc * a_dst[hh * DDD + lane];
#pragma unroll
    for (int off = 32; off; off >>= 1){
        s1 += __shfl_xor(s1, off);
        s2 += __shfl_xor(s2, off);
    }
    if (lane == 0){
        asb[(size_t)n * HHH + hh] = s1;
        adb[(size_t)n * HHH + hh] = s2;
    }
}

// ---------------- main GEMM: gelu(A) @ W via split-bf16 MFMA, fused alpha, bf16 out ----------------
__global__ __launch_bounds__(256) void gemm_mfma(const float* __restrict__ A,
                                                 const unsigned short* __restrict__ Bhi,
                                                 const unsigned short* __restrict__ Blo,
                                                 const unsigned short* __restrict__ WAhi,
                                                 const unsigned short* __restrict__ WAlo,
                                                 unsigned short* __restrict__ C,
                                                 float* __restrict__ asb,
                                                 float* __restrict__ adb){
    int tid  = threadIdx.x;
    int lane = tid & 63, wave = tid >> 6;
    int wr = wave >> 1, wc = wave & 1;
    int rowBase = blockIdx.y * 128 + wr * 64;
    int colBase = blockIdx.x * 128 + wc * 64;
    int fr = lane & 15;      // fragment row (A) / col (B,D)
    int kg = lane >> 4;      // k-group 0..3
    bool doAlpha = (blockIdx.x == 0) && (wc == 0);

    v4f acc[4][4];
#pragma unroll
    for (int mi = 0; mi < 4; ++mi)
#pragma unroll
        for (int ni = 0; ni < 4; ++ni) acc[mi][ni] = (v4f){0.f, 0.f, 0.f, 0.f};
    v4f acca[4];
#pragma unroll
    for (int mi = 0; mi < 4; ++mi) acca[mi] = (v4f){0.f, 0.f, 0.f, 0.f};

    const float* aptr[4];
#pragma unroll
    for (int mi = 0; mi < 4; ++mi){
        int r = rowBase + mi * 16 + fr;
        if (r >= NN) r = NN - 1;                  // clamp; stores guarded below
        aptr[mi] = A + (size_t)r * CCH + kg * 8;
    }
    const unsigned short* bhp[4];
    const unsigned short* blp[4];
#pragma unroll
    for (int ni = 0; ni < 4; ++ni){
        int c = colBase + ni * 16 + fr;
        bhp[ni] = Bhi + (size_t)c * CCH + kg * 8;
        blp[ni] = Blo + (size_t)c * CCH + kg * 8;
    }
    const unsigned short* wahp = WAhi + (size_t)fr * CCH + kg * 8;
    const unsigned short* walp = WAlo + (size_t)fr * CCH + kg * 8;

    for (int kc = 0; kc < CCH; kc += 32){
        v8s ah[4], al[4], bh[4], bl[4];
#pragma unroll
        for (int mi = 0; mi < 4; ++mi){
            float4 v0 = *(const float4*)(aptr[mi] + kc);
            float4 v1 = *(const float4*)(aptr[mi] + kc + 4);
            float f[8] = {v0.x, v0.y, v0.z, v0.w, v1.x, v1.y, v1.z, v1.w};
            v8s hi, lo;
#pragma unroll
            for (int j = 0; j < 8; ++j){
                float g = gelu_f(f[j]);
                unsigned short hb = f2bf(g);
                hi[j] = (short)hb;
                lo[j] = (short)f2bf(g - bf2f(hb));
            }
            ah[mi] = hi; al[mi] = lo;
        }
#pragma unroll
        for (int ni = 0; ni < 4; ++ni){
            bh[ni] = *(const v8s*)(bhp[ni] + kc);
            bl[ni] = *(const v8s*)(blp[ni] + kc);
        }
#pragma unroll
        for (int mi = 0; mi < 4; ++mi)
#pragma unroll
            for (int ni = 0; ni < 4; ++ni){
                acc[mi][ni] = __builtin_amdgcn_mfma_f32_16x16x32_bf16(ah[mi], bh[ni], acc[mi][ni], 0, 0, 0);
                acc[mi][ni] = __builtin_amdgcn_mfma_f32_16x16x32_bf16(al[mi], bh[ni], acc[mi][ni], 0, 0, 0);
                acc[mi][ni] = __builtin_amdgcn_mfma_f32_16x16x32_bf16(ah[mi], bl[ni], acc[mi][ni], 0, 0, 0);
            }
        if (doAlpha){
            v8s wh = *(const v8s*)(wahp + kc);
            v8s wl = *(const v8s*)(walp + kc);
#pragma unroll
            for (int mi = 0; mi < 4; ++mi){
                acca[mi] = __builtin_amdgcn_mfma_f32_16x16x32_bf16(ah[mi], wh, acca[mi], 0, 0, 0);
                acca[mi] = __builtin_amdgcn_mfma_f32_16x16x32_bf16(al[mi], wh, acca[mi], 0, 0, 0);
                acca[mi] = __builtin_amdgcn_mfma_f32_16x16x32_bf16(ah[mi], wl, acca[mi], 0, 0, 0);
            }
        }
    }

    // D layout: col = lane&15 (=fr), row = (lane>>4)*4 + j (=kg*4+j)
#pragma unroll
    for (int mi = 0; mi < 4; ++mi)
#pragma unroll
        for (int j = 0; j < 4; ++j){
            int r = rowBase + mi * 16 + kg * 4 + j;
            if (r < NN){
#pragma unroll
                for (int ni = 0; ni < 4; ++ni)
                    C[(size_t)r * CCH + colBase + ni * 16 + fr] = f2bf(acc[mi][ni][j]);
            }
        }
    if (doAlpha){
#pragma unroll
        for (int mi = 0; mi < 4; ++mi)
#pragma unroll
            for (int j = 0; j < 4; ++j){
                int r = rowBase + mi * 16 + kg * 4 + j;
                if (r < NN){
                    float val = acca[mi][j];
                    if (fr < 4)      asb[(size_t)r * HHH + fr]       = val;
                    else if (fr < 8) adb[(size_t)r * HHH + (fr - 4)] = val;
                }
            }
    }
}

// ---------------- per-node softmax + aggregation: ONE WAVE PER NODE, bf16 payload ----------------
#define LOADG(gg, U0, U1, U2, U3, A0, A1, A2, A3)                      \
    { int _b = (gg) << 2;                                              \
      int _i0 = ix_w[_b], _i1 = ix_w[_b + 1];                          \
      int _i2 = ix_w[_b + 2], _i3 = ix_w[_b + 3];                      \
      A0 = al_w[(_b + 0) * HHH + hc];                                  \
      A1 = al_w[(_b + 1) * HHH + hc];                                  \
      A2 = al_w[(_b + 2) * HHH + hc];                                  \
      A3 = al_w[(_b + 3) * HHH + hc];                                  \
      U0 = *(const uint2*)(h + (size_t)_i0 * CCH + coff);              \
      U1 = *(const uint2*)(h + (size_t)_i1 * CCH + coff);              \
      U2 = *(const uint2*)(h + (size_t)_i2 * CCH + coff);              \
      U3 = *(const uint2*)(h + (size_t)_i3 * CCH + coff); }

#define CONSUME(U0, U1, U2, U3, A0, A1, A2, A3)                        \
    { float4 _v0 = up4(U0), _v1 = up4(U1), _v2 = up4(U2), _v3 = up4(U3); \
      acc.x += _v0.x * A0 + _v1.x * A1 + _v2.x * A2 + _v3.x * A3;      \
      acc.y += _v0.y * A0 + _v1.y * A1 + _v2.y * A2 + _v3.y * A3;      \
      acc.z += _v0.z * A0 + _v1.z * A1 + _v2.z * A2 + _v3.z * A3;      \
      acc.w += _v0.w * A0 + _v1.w * A1 + _v2.w * A2 + _v3.w * A3; }

__global__ __launch_bounds__(256) void agg_k(const unsigned short* __restrict__ h,
                                             const float* __restrict__ asrc,
                                             const float* __restrict__ adst,
                                             const float* __restrict__ bias,
                                             const int* __restrict__ row_ptr,
                                             const int* __restrict__ csr_src,
                                             float* __restrict__ out){
    __shared__ float s_al[4][64 * HHH];
    __shared__ int   s_ix[4][64];

    int wave = threadIdx.x >> 6, lane = threadIdx.x & 63;
    int n = blockIdx.x * 4 + wave;
    int row0 = row_ptr[n];
    int deg  = row_ptr[n + 1] - row0;
    float4 ad = *(const float4*)(adst + (size_t)n * HHH);
    int coff = lane << 2;        // this lane's 4 channels
    int hc   = lane >> 4;        // head those channels belong to
    float* al_w = s_al[wave];
    int*   ix_w = s_ix[wave];
    float4 acc = make_float4(0.f, 0.f, 0.f, 0.f);

    if (deg <= 64){
        // ---- fast path: lane k = edge k ----
        int k = lane;
        int s = 0;
        float e0 = -INFINITY, e1 = -INFINITY, e2 = -INFINITY, e3 = -INFINITY;
        if (k < deg){
            s = csr_src[row0 + k];
            float4 as = *(const float4*)(asrc + (size_t)s * HHH);
            e0 = lrelu(as.x + ad.x); e1 = lrelu(as.y + ad.y);
            e2 = lrelu(as.z + ad.z); e3 = lrelu(as.w + ad.w);
        }
        float m0 = e0, m1 = e1, m2 = e2, m3 = e3;
#pragma unroll
        for (int off = 32; off; off >>= 1){
            m0 = fmaxf(m0, __shfl_xor(m0, off));
            m1 = fmaxf(m1, __shfl_xor(m1, off));
            m2 = fmaxf(m2, __shfl_xor(m2, off));
            m3 = fmaxf(m3, __shfl_xor(m3, off));
        }
        float x0 = 0.f, x1 = 0.f, x2 = 0.f, x3 = 0.f;
        if (k < deg){
            x0 = __expf(e0 - m0); x1 = __expf(e1 - m1);
            x2 = __expf(e2 - m2); x3 = __expf(e3 - m3);
        }
        float z0 = x0, z1 = x1, z2 = x2, z3 = x3;
#pragma unroll
        for (int off = 32; off; off >>= 1){
            z0 += __shfl_xor(z0, off);
            z1 += __shfl_xor(z1, off);
            z2 += __shfl_xor(z2, off);
            z3 += __shfl_xor(z3, off);
        }
        if (k < deg){
            float4 alv;
            alv.x = x0 / (z0 + 1e-16f);
            alv.y = x1 / (z1 + 1e-16f);
            alv.z = x2 / (z2 + 1e-16f);
            alv.w = x3 / (z3 + 1e-16f);
            ix_w[k] = s;
            *(float4*)&al_w[k * HHH] = alv;
        }
        // ---- pipelined gather: groups of 4 rows, 2-slot double-buffer ----
        int ng = deg >> 2;
        uint2 vA0, vA1, vA2, vA3, vB0, vB1, vB2, vB3;
        float aA0, aA1, aA2, aA3, aB0, aB1, aB2, aB3;
        if (ng > 0) LOADG(0, vA0, vA1, vA2, vA3, aA0, aA1, aA2, aA3);
        if (ng > 1) LOADG(1, vB0, vB1, vB2, vB3, aB0, aB1, aB2, aB3);
        for (int g = 0; g < ng; g += 2){
            if (g + 2 < ng) {
                CONSUME(vA0, vA1, vA2, vA3, aA0, aA1, aA2, aA3);
                LOADG(g + 2, vA0, vA1, vA2, vA3, aA0, aA1, aA2, aA3);
            } else {
                CONSUME(vA0, vA1, vA2, vA3, aA0, aA1, aA2, aA3);
            }
            if (g + 1 < ng){
                if (g + 3 < ng) {
                    CONSUME(vB0, vB1, vB2, vB3, aB0, aB1, aB2, aB3);
                    LOADG(g + 3, vB0, vB1, vB2, vB3, aB0, aB1, aB2, aB3);
                } else {
                    CONSUME(vB0, vB1, vB2, vB3, aB0, aB1, aB2, aB3);
                }
            }
        }
        for (int kk = ng << 2; kk < deg; ++kk){
            int i0 = ix_w[kk];
            float a0 = al_w[kk * HHH + hc];
            float4 v0 = up4(*(const uint2*)(h + (size_t)i0 * CCH + coff));
            acc.x += v0.x * a0; acc.y += v0.y * a0; acc.z += v0.z * a0; acc.w += v0.w * a0;
        }
    } else {
        // ---- generic path: online softmax over 64-edge chunks ----
        float m0 = -INFINITY, m1 = -INFINITY, m2 = -INFINITY, m3 = -INFINITY;
        float z0 = 0.f, z1 = 0.f, z2 = 0.f, z3 = 0.f;
        for (int c0 = 0; c0 < deg; c0 += 64){
            int k = c0 + lane;
            float e0 = -INFINITY, e1 = -INFINITY, e2 = -INFINITY, e3 = -INFINITY;
            if (k < deg){
                int s = csr_src[row0 + k];
                float4 as = *(const float4*)(asrc + (size_t)s * HHH);
                e0 = lrelu(as.x + ad.x); e1 = lrelu(as.y + ad.y);
                e2 = lrelu(as.z + ad.z); e3 = lrelu(as.w + ad.w);
            }
            float c0m = e0, c1m = e1, c2m = e2, c3m = e3;
#pragma unroll
            for (int off = 32; off; off >>= 1){
                c0m = fmaxf(c0m, __shfl_xor(c0m, off));
                c1m = fmaxf(c1m, __shfl_xor(c1m, off));
                c2m = fmaxf(c2m, __shfl_xor(c2m, off));
                c3m = fmaxf(c3m, __shfl_xor(c3m, off));
            }
            float n0 = fmaxf(m0, c0m), n1 = fmaxf(m1, c1m);
            float n2 = fmaxf(m2, c2m), n3 = fmaxf(m3, c3m);
            float x0 = 0.f, x1 = 0.f, x2 = 0.f, x3 = 0.f;
            if (k < deg){
                x0 = __expf(e0 - n0); x1 = __expf(e1 - n1);
                x2 = __expf(e2 - n2); x3 = __expf(e3 - n3);
            }
            float s0 = x0, s1 = x1, s2 = x2, s3 = x3;
#pragma unroll
            for (int off = 32; off; off >>= 1){
                s0 += __shfl_xor(s0, off);
                s1 += __shfl_xor(s1, off);
                s2 += __shfl_xor(s2, off);
                s3 += __shfl_xor(s3, off);
            }
            z0 = z0 * ((m0 == -INFINITY) ? 0.f : __expf(m0 - n0)) + s0;
            z1 = z1 * ((m1 == -INFINITY) ? 0.f : __expf(m1 - n1)) + s1;
            z2 = z2 * ((m2 == -INFINITY) ? 0.f : __expf(m2 - n2)) + s2;
            z3 = z3 * ((m3 == -INFINITY) ? 0.f : __expf(m3 - n3)) + s3;
            m0 = n0; m1 = n1; m2 = n2; m3 = n3;
        }
        float iz0 = 1.f / (z0 + 1e-16f), iz1 = 1.f / (z1 + 1e-16f);
        float iz2 = 1.f / (z2 + 1e-16f), iz3 = 1.f / (z3 + 1e-16f);
        for (int c0 = 0; c0 < deg; c0 += 64){
            int k = c0 + lane;
            if (k < deg){
                int s = csr_src[row0 + k];
                float4 as = *(const float4*)(asrc + (size_t)s * HHH);
                float4 alv;
                alv.x = __expf(lrelu(as.x + ad.x) - m0) * iz0;
                alv.y = __expf(lrelu(as.y + ad.y) - m1) * iz1;
                alv.z = __expf(lrelu(as.z + ad.z) - m2) * iz2;
                alv.w = __expf(lrelu(as.w + ad.w) - m3) * iz3;
                ix_w[lane] = s;
                *(float4*)&al_w[lane * HHH] = alv;
            }
            int cnt = deg - c0; if (cnt > 64) cnt = 64;
            for (int j = 0; j < cnt; ++j){
                int i0 = ix_w[j];
                float a0 = al_w[j * HHH + hc];
                float4 v0 = up4(*(const uint2*)(h + (size_t)i0 * CCH + coff));
                acc.x += v0.x * a0; acc.y += v0.y * a0; acc.z += v0.z * a0; acc.w += v0.w * a0;
            }
        }
    }

    float4 bv = *(const float4*)(bias + coff);
    acc.x += bv.x; acc.y += bv.y; acc.z += bv.z; acc.w += bv.w;
    *(float4*)(out + (size_t)n * CCH + coff) = acc;
}

// ---------------- graph boundary pointers (batch is sorted) ----------------
__global__ void gptr_k(const int* __restrict__ batch, int* __restrict__ gptr){
    int i = blockIdx.x * 256 + threadIdx.x;
    if (i >= NN) return;
    int bi = batch[i];
    int bp = (i == 0) ? -1 : batch[i - 1];
    for (int g = bp + 1; g <= bi; ++g) gptr[g] = i;
    if (i == NN - 1){
        for (int g = bi + 1; g <= BB; ++g) gptr[g] = NN;
    }
}

// ---------------- pooling stage 1 ----------------
__global__ __launch_bounds__(256) void pool1_k(const float* __restrict__ h,
                                               const int* __restrict__ gptr,
                                               float* __restrict__ part){
    const int S1 = BB * PCHUNK * CCH;
    int b = blockIdx.x, j = blockIdx.y, c = threadIdx.x;
    int s = gptr[b], e = gptr[b + 1];
    int len = e - s;
    int per = (len + PCHUNK - 1) / PCHUNK;
    int r0 = s + j * per;
    int r1 = r0 + per; if (r1 > e) r1 = e;
    float mn = INFINITY, mx = -INFINITY, sm = 0.f;
    int n = r0;
    for (; n + 4 <= r1; n += 4){
        float v0 = h[(size_t)(n + 0) * CCH + c];
        float v1 = h[(size_t)(n + 1) * CCH + c];
        float v2 = h[(size_t)(n + 2) * CCH + c];
        float v3 = h[(size_t)(n + 3) * CCH + c];
        mn = fminf(mn, fminf(fminf(v0, v1), fminf(v2, v3)));
        mx = fmaxf(mx, fmaxf(fmaxf(v0, v1), fmaxf(v2, v3)));
        sm += (v0 + v1) + (v2 + v3);
    }
    for (; n < r1; ++n){
        float v = h[(size_t)n * CCH + c];
        mn = fminf(mn, v); mx = fmaxf(mx, v); sm += v;
    }
    size_t o = ((size_t)b * PCHUNK + j) * CCH + c;
    part[o] = mn; part[S1 + o] = mx; part[2 * (size_t)S1 + o] = sm;
}

// ---------------- pooling stage 2 ----------------
__global__ __launch_bounds__(256) void pool2_k(const float* __restrict__ part,
                                               const int* __restrict__ gptr,
                                               float* __restrict__ gbuf){
    const int S1 = BB * PCHUNK * CCH;
    int b = blockIdx.x, c = threadIdx.x;
    float mn = INFINITY, mx = -INFINITY, sm = 0.f;
#pragma unroll
    for (int j = 0; j < PCHUNK; ++j){
        size_t o = ((size_t)b * PCHUNK + j) * CCH + c;
        mn = fminf(mn, part[o]);
        mx = fmaxf(mx, part[S1 + o]);
        sm += part[2 * (size_t)S1 + o];
    }
    int cnt = gptr[b + 1] - gptr[b];
    float mean = sm / fmaxf((float)cnt, 1.0f);
    if (cnt == 0){ mn = 0.f; mx = 0.f; }
    gbuf[b * 4 * CCH + 0 * CCH + c] = mn;
    gbuf[b * 4 * CCH + 1 * CCH + c] = mx;
    gbuf[b * 4 * CCH + 2 * CCH + c] = mean;
    gbuf[b * 4 * CCH + 3 * CCH + c] = sm;
}

// ---------------- head: gelu(g) @ head_W + head_b ----------------
__global__ __launch_bounds__(128) void head_k(const float* __restrict__ gbuf,
                                              const float* __restrict__ head_W,
                                              const float* __restrict__ head_b,
                                              float* __restrict__ out){
    __shared__ float gs[4 * CCH];
    int b = blockIdx.x;
    int o = threadIdx.x;
    for (int k = o; k < 4 * CCH; k += 128) gs[k] = gelu_f(gbuf[b * 4 * CCH + k]);
    __syncthreads();
    float acc = head_b[o];
    for (int k = 0; k < 4 * CCH; ++k) acc += gs[k] * head_W[k * NOUTP + o];
    out[b * NOUTP + o] = acc;
}

extern "C" void kernel_launch(void* const* d_in, const int* in_sizes, int n_in,
                              void* d_out, int out_size, void* d_ws, size_t ws_size,
                              hipStream_t stream){
    const float* x        = (const float*)d_in[0];
    const int*   ei       = (const int*)  d_in[1];
    const int*   batch    = (const int*)  d_in[2];
    const float* W0       = (const float*)d_in[3];
    const float* a_src0   = (const float*)d_in[4];
    const float* a_dst0   = (const float*)d_in[5];
    const float* b0       = (const float*)d_in[6];
    const float* Ws       = (const float*)d_in[7];
    const float* a_srcs   = (const float*)d_in[8];
    const float* a_dsts   = (const float*)d_in[9];
    const float* bs       = (const float*)d_in[10];
    const float* head_W   = (const float*)d_in[11];
    const float* head_b   = (const float*)d_in[12];
    float* out = (float*)d_out;

    char* p = (char*)d_ws;
    float* buf0 = (float*)p;                   p += (size_t)NN * CCH * 4;   // fp32 agg output
    unsigned short* buf1 = (unsigned short*)p; p += (size_t)NN * CCH * 2;   // bf16 payload h_l
    float* asb  = (float*)p;                   p += (size_t)NN * HHH * 4;
    float* adb  = (float*)p;                   p += (size_t)NN * HHH * 4;
    int* row_ptr = (int*)p;                    p += 120016;                 // (N+1)*4 padded
    int* cnt     = (int*)p;                    p += (size_t)NN * 4;
    int* csr_src = (int*)p;                    p += (size_t)ETOT * 4;
    float* gbuf  = (float*)p;                  p += (size_t)BB * 4 * CCH * 4;
    int* gptr    = (int*)p;                    p += 208;
    unsigned short* wthi = (unsigned short*)p; p += (size_t)(NLAY - 1) * CCH * CCH * 2;
    unsigned short* wtlo = (unsigned short*)p; p += (size_t)(NLAY - 1) * CCH * CCH * 2;
    unsigned short* wahi = (unsigned short*)p; p += (size_t)(NLAY - 1) * 16 * CCH * 2;
    unsigned short* walo = (unsigned short*)p; p += (size_t)(NLAY - 1) * 16 * CCH * 2;
    float* pscr = (float*)p;                   p += (size_t)3 * BB * PCHUNK * CCH * 4;  // pool partials

    // ---- CSR build + weight prep ----
    hipMemsetAsync(cnt, 0, (size_t)NN * 4, stream);
    count_k<<<(ETOT + 255) / 256, 256, 0, stream>>>(ei, cnt);
    scan_k<<<1, 1024, 0, stream>>>(cnt, row_ptr);
    hipMemsetAsync(cnt, 0, (size_t)NN * 4, stream);
    scatter_k<<<(ETOT + 255) / 256, 256, 0, stream>>>(ei, row_ptr, cnt, csr_src);
    gptr_k<<<(NN + 255) / 256, 256, 0, stream>>>(batch, gptr);
    wconv_k<<<dim3(NLAY - 1, 8), 256, 0, stream>>>(Ws, wthi, wtlo);
    waconv_k<<<NLAY - 1, 256, 0, stream>>>(Ws, a_srcs, a_dsts, wahi, walo);

    // ---- layer 0 (fused h0 + alpha) ----
    l0_fused<<<NN, 256, 0, stream>>>(x, W0, a_src0, a_dst0, buf1, asb, adb);
    agg_k<<<NN / 4, 256, 0, stream>>>(buf1, asb, adb, b0, row_ptr, csr_src, buf0);

    // ---- layers 1..9 (alpha fused into gemm, bf16 payload out) ----
    dim3 ggrid(2, (NN + 127) / 128);
    for (int l = 1; l < NLAY; ++l){
        const unsigned short* whl = wthi + (size_t)(l - 1) * CCH * CCH;
        const unsigned short* wll = wtlo + (size_t)(l - 1) * CCH * CCH;
        const unsigned short* wal_h = wahi + (size_t)(l - 1) * 16 * CCH;
        const unsigned short* wal_l = walo + (size_t)(l - 1) * 16 * CCH;
        const float* bl  = bs + (size_t)(l - 1) * CCH;
        gemm_mfma<<<ggrid, 256, 0, stream>>>(buf0, whl, wll, wal_h, wal_l, buf1, asb, adb);
        agg_k<<<NN / 4, 256, 0, stream>>>(buf1, asb, adb, bl, row_ptr, csr_src, buf0);
    }

    // ---- readout ----
    dim3 pgrid(BB, PCHUNK);
    pool1_k<<<pgrid, 256, 0, stream>>>(buf0, gptr, pscr);
    pool2_k<<<BB, 256, 0, stream>>>(pscr, gptr, gbuf);
    head_k<<<BB, 128, 0, stream>>>(gbuf, head_W, head_b, out);
}